// Round 8
// baseline (803.089 us; speedup 1.0000x reference)
//
#include <hip/hip_runtime.h>

// ---------------------------------------------------------------------------
// AttentionStack: 6-layer transformer, B=2, SEQ=1024, E=576, H=16, DK=36.
// Inputs/outputs dtype auto-detected (f32 vs bf16) at runtime; internal
// pipeline: bf16 MFMA GEMMs (128x64 tiles, 8-WAVE blocks for TLP, LDS-staged
// 1-phase, split-K via fp32 partial buffers -- no atomics; reduction fused
// into the next LN / output kernel) + fp32 residual stream. Attention:
// swapped-operand flash, 64-row q-tiles (4 q-waves x 2 kv-waves) to cut
// the L2-bound K/V re-read 4x (R7 analysis: old 16-row tiles re-read
// ~1.07 GB/layer from L2 = the 34.5us floor).
// ---------------------------------------------------------------------------

#define E_    576
#define SEQ_  1024
#define B_    2
#define NH_   16
#define DK_   36
#define DKP_  64          // DK padded to 64 for MFMA K-steps of 32
#define NL_   6
#define FF_   2304
#define ROWS_ 2048        // B_*SEQ_
#define PSTRIDE_ 1179648  // 2048*576 floats per split-K partial slice

typedef unsigned short u16;
typedef unsigned int u32;
typedef float f32x4 __attribute__((ext_vector_type(4)));
typedef __bf16 bf16x8 __attribute__((ext_vector_type(8)));
typedef __bf16 bf16x4 __attribute__((ext_vector_type(4)));

#define MFMA16(a, b, c) __builtin_amdgcn_mfma_f32_16x16x32_bf16((a), (b), (c), 0, 0, 0)

__device__ __forceinline__ float bf2f(u16 u) {
    return __uint_as_float(((unsigned)u) << 16);
}
__device__ __forceinline__ u16 f2bf(float f) {
    unsigned u = __float_as_uint(f);
    u += 0x7fffu + ((u >> 16) & 1u);   // round-to-nearest-even
    return (u16)(u >> 16);
}
__device__ __forceinline__ float load_in(const void* p, size_t i, int isf32) {
    return isf32 ? ((const float*)p)[i] : bf2f(((const u16*)p)[i]);
}
__device__ __forceinline__ bf16x8 ldg8(const u16* p) {
    uint4 u = *(const uint4*)p;        // 16B aligned by construction
    bf16x8 r;
    __builtin_memcpy(&r, &u, 16);
    return r;
}
// async global->LDS, 16B per lane; LDS dest = wave-uniform base + lane*16
__device__ __forceinline__ void gload_lds16(const u16* g, u16* l) {
    __builtin_amdgcn_global_load_lds(
        (const __attribute__((address_space(1))) unsigned int*)g,
        (__attribute__((address_space(3))) unsigned int*)l, 16, 0, 0);
}

// ---------------------------------------------------------------------------
// Dtype detect: f32 data read as bf16 u16s shows huge magnitudes.
// ---------------------------------------------------------------------------
__global__ void detect_kernel(const u16* __restrict__ x, int* __restrict__ flag)
{
    __shared__ float red[4];
    int lane = threadIdx.x & 63, wave = threadIdx.x >> 6;
    float mx = 0.f;
    for (int i = threadIdx.x; i < 4096; i += 256) {
        float v = fabsf(bf2f(x[i]));
        if (v < 3e38f) mx = fmaxf(mx, v);
    }
    for (int off = 1; off < 64; off <<= 1) mx = fmaxf(mx, __shfl_xor(mx, off));
    if (lane == 0) red[wave] = mx;
    __syncthreads();
    if (threadIdx.x == 0) {
        float m = fmaxf(fmaxf(red[0], red[1]), fmaxf(red[2], red[3]));
        *flag = (m > 1e6f) ? 1 : 0;
    }
}

// ---------------------------------------------------------------------------
// Weight repack v4: W[K][N] -> W^T[N][K] bf16. 64x64 tiles. (R7: ILP fix
// raised VGPR 8->32 but dur unchanged at ~41us -- floor is the strided
// access pattern, not ILP. Kept; not the top lever.)
// grid (972, 1, 6), block 256.
// ---------------------------------------------------------------------------
__global__ __launch_bounds__(256) void repack_kernel(
    const void* __restrict__ wq, const void* __restrict__ wk,
    const void* __restrict__ wv, const void* __restrict__ wo,
    const void* __restrict__ w1, const void* __restrict__ w2,
    u16* __restrict__ wT, const int* __restrict__ flagp)
{
    __shared__ u32 tile[64 * 33];           // [row][col-pair], pad 33 words
    int isf32 = *flagp;
    int idx = blockIdx.x, l = blockIdx.z;
    const void* src;
    u16* dst;
    size_t sbase;
    int R, C, cx, ry;
    if (idx < 324) {                        // wq/wk/wv/wo: 576x576, 81 tiles ea
        int t4 = idx / 81, rem = idx - t4 * 81;
        ry = rem / 9; cx = rem % 9; R = 576; C = 576;
        src = (t4 == 0) ? wq : (t4 == 1) ? wk : (t4 == 2) ? wv : wo;
        sbase = (size_t)l * 331776;
        dst = wT + (size_t)l * 3981312 + t4 * 331776;
    } else if (idx < 648) {                 // w1: 576x2304 -> 2304x576
        int rem = idx - 324;
        ry = rem / 36; cx = rem % 36; R = 576; C = 2304;
        src = w1; sbase = (size_t)l * 1327104;
        dst = wT + (size_t)l * 3981312 + 1327104;
    } else {                                // w2: 2304x576 -> 576x2304
        int rem = idx - 648;
        ry = rem / 9; cx = rem % 9; R = 2304; C = 576;
        src = w2; sbase = (size_t)l * 1327104;
        dst = wT + (size_t)l * 3981312 + 2654208;
    }
    int r0 = ry * 64, c0 = cx * 64;
    int t = threadIdx.x;
    // load: thread t covers row (t>>4)+16i, 4-float chunk t&15.
    // Phase 1: issue all 4 independent 16B loads (ILP).
    int chunk = t & 15, row = t >> 4;
    f32x4 vf4[4];
    uint2 vb2[4];
    #pragma unroll
    for (int i = 0; i < 4; i++) {
        int rr = row + i * 16;
        size_t g = sbase + (size_t)(r0 + rr) * C + c0 + chunk * 4;
        if (isf32) vf4[i] = *(const f32x4*)((const float*)src + g);
        else       vb2[i] = *(const uint2*)((const u16*)src + g);
    }
    // Phase 2: pack + LDS write.
    #pragma unroll
    for (int i = 0; i < 4; i++) {
        int rr = row + i * 16;
        u32 lo, hi;
        if (isf32) {
            lo = (u32)f2bf(vf4[i][0]) | ((u32)f2bf(vf4[i][1]) << 16);
            hi = (u32)f2bf(vf4[i][2]) | ((u32)f2bf(vf4[i][3]) << 16);
        } else {
            lo = vb2[i].x; hi = vb2[i].y;
        }
        tile[rr * 33 + chunk * 2] = lo;
        tile[rr * 33 + chunk * 2 + 1] = hi;
    }
    __syncthreads();
    // store: thread t covers word-pair p2=t&15 of output row nn=(t>>4)+16i.
    int p2 = t & 15, nl = t >> 4;
    #pragma unroll
    for (int i = 0; i < 4; i++) {
        int nn = nl + i * 16;
        int hw = nn >> 1, sh = (nn & 1) * 16;
        u32 wA = tile[(4 * p2)     * 33 + hw];
        u32 wB = tile[(4 * p2 + 1) * 33 + hw];
        u32 wC = tile[(4 * p2 + 2) * 33 + hw];
        u32 wD = tile[(4 * p2 + 3) * 33 + hw];
        u32 a = (wA >> sh) & 0xffffu, b = (wB >> sh) & 0xffffu;
        u32 c = (wC >> sh) & 0xffffu, d = (wD >> sh) & 0xffffu;
        uint2 o;
        o.x = a | (b << 16);
        o.y = c | (d << 16);
        ((uint2*)(dst + (size_t)(c0 + nn) * R + r0))[p2] = o;
    }
}

// ---------------------------------------------------------------------------
// Embed: h = rightshift(x, sos) + concat(pe0[t], pe1[h], pe2[w]); fp32 out.
// ---------------------------------------------------------------------------
__global__ void embed_kernel(
    const void* __restrict__ x, const void* __restrict__ sos,
    const void* __restrict__ pe0, const void* __restrict__ pe1,
    const void* __restrict__ pe2, float* __restrict__ h,
    const int* __restrict__ flagp)
{
    int isf32 = *flagp;
    int row = blockIdx.x;        // b*1024 + s
    int e = threadIdx.x;
    int s = row & 1023;
    float v = (s == 0) ? load_in(sos, e, isf32)
                       : load_in(x, (size_t)(row - 1) * E_ + e, isf32);
    int t = s >> 8, hh = (s >> 4) & 15, ww = s & 15;
    float p = (e < 192) ? load_in(pe0, t * 192 + e, isf32)
            : (e < 384) ? load_in(pe1, hh * 192 + e - 192, isf32)
                        : load_in(pe2, ww * 192 + e - 384, isf32);
    h[(size_t)row * E_ + e] = v + p;
}

// ---------------------------------------------------------------------------
// LayerNorm + fused split-K reduce: h += sum(parts[0..NPART)); y = LN(h).
// NPART=0: plain LN (layer 0 entry). NPART=3: after O-proj. NPART=4: after
// MLP2 (entry of layers 1..5). One wave per row. (R5: replaced ~50M scalar
// f32 atomics/forward with partials + this fused streaming reduce: -74us.)
// ---------------------------------------------------------------------------
template <int NPART>
__global__ __launch_bounds__(256) void ln_kernel(
    float* __restrict__ h, u16* __restrict__ y,
    const float* __restrict__ parts,
    const void* __restrict__ sc, const void* __restrict__ bi,
    int off0, const int* __restrict__ flagp)
{
    int isf32 = *flagp;
    int lane = threadIdx.x & 63, wave = threadIdx.x >> 6;
    int row = blockIdx.x * 4 + wave;
    float* hr = h + (size_t)row * E_;
    float v[9], s = 0.f, sq = 0.f;
    #pragma unroll
    for (int j = 0; j < 9; j++) {
        int e = lane + j * 64;
        float t = hr[e];
        #pragma unroll
        for (int pk = 0; pk < NPART; pk++)
            t += parts[(size_t)pk * PSTRIDE_ + (size_t)row * E_ + e];
        if (NPART > 0) hr[e] = t;   // persist updated residual stream
        v[j] = t;
        s += t;
        sq += t * t;
    }
    for (int off = 1; off < 64; off <<= 1) {
        s += __shfl_xor(s, off);
        sq += __shfl_xor(sq, off);
    }
    float mean = s * (1.0f / E_);
    float var = sq * (1.0f / E_) - mean * mean;
    float r = rsqrtf(var + 1e-5f);
    #pragma unroll
    for (int j = 0; j < 9; j++) {
        int e = lane + j * 64;
        float sce = load_in(sc, off0 + e, isf32);
        float bie = load_in(bi, off0 + e, isf32);
        y[(size_t)row * E_ + e] = f2bf((v[j] - mean) * r * sce + bie);
    }
}

// ---------------------------------------------------------------------------
// GEMM v4 (8-wave TLP): C[m,n] = sum_k A[m,k]*Bt[n,k]. Block tile
// 128(M)x64(N), 512 threads = 8 waves in 4x2 (wx=M-quarter, wy=N-half);
// each wave one 32x32 output (acc[2][2]). (R6: 4->8 waves was -24us; the
// residual GEMM cost is structural per-dispatch overhead, not TLP.)
// MODE 0: QKV (z picks wq/wk/wv; writes q(scaled)/k/vt padded to DKP)
// MODE 1: O-proj partials: pout[kz] = A@woT (+bo on kz==0)   [no atomics]
// MODE 2: MLP1:  y1 = gelu2(A@w1T + b1)  (N stride FF_)
// MODE 3: MLP2 partials: pout[kz] = A@w2T (+b2 on kz==0)     [no atomics]
// ---------------------------------------------------------------------------
template <int MODE, int SPLITK>
__global__ __launch_bounds__(512) void gemm_kernel(
    const u16* __restrict__ A, const u16* __restrict__ BtBase, int K,
    const void* __restrict__ bias, int boff, float* __restrict__ pout,
    u16* __restrict__ out, u16* __restrict__ qb, u16* __restrict__ kb,
    u16* __restrict__ vtb, const int* __restrict__ flagp)
{
    __shared__ u16 lA[8192];     // 128 rows x 64 cols bf16 (16 KB)
    __shared__ u16 lB[4096];     //  64 rows x 64 cols bf16 ( 8 KB)
    int t = threadIdx.x;
    int lane = t & 63, wave = t >> 6;      // wave 0..7
    int lw = lane & 15, lq = lane >> 4;
    int wx = wave >> 1, wy = wave & 1;     // wx 0..3 (M), wy 0..1 (N)
    int m0 = blockIdx.x * 128, n0 = blockIdx.y * 64;
    int z = blockIdx.z / SPLITK, kz = blockIdx.z % SPLITK;
    int Ks = K / SPLITK, kbase = kz * Ks;

    const u16* Bt = BtBase + (MODE == 0 ? (size_t)z * 331776 : 0);
    int rowS = t >> 3;                      // 0..63
    int gc = (t & 7) ^ (rowS & 7);
    const u16* gA = A + (size_t)(m0 + rowS) * K + kbase + gc * 8;
    const u16* gB = Bt + (size_t)(n0 + rowS) * K + kbase + gc * 8;
    size_t rstep = (size_t)64 * K;

    f32x4 acc[2][2];
    for (int mi = 0; mi < 2; mi++)
        for (int ni = 0; ni < 2; ni++)
            for (int r = 0; r < 4; r++) acc[mi][ni][r] = 0.f;

    for (int kc = 0; kc < Ks; kc += 64) {
        gload_lds16(gA + kc,         &lA[t * 8]);        // A rows 0..63
        gload_lds16(gA + rstep + kc, &lA[4096 + t * 8]); // A rows 64..127
        gload_lds16(gB + kc,         &lB[t * 8]);        // B rows 0..63
        __syncthreads();
        #pragma unroll
        for (int ks = 0; ks < 2; ks++) {
            int csw = ((ks * 4 + lq) ^ (lw & 7)) * 8;
            bf16x8 bf0 = ldg8(&lB[(wy * 32 + lw) * 64 + csw]);
            bf16x8 bf1 = ldg8(&lB[(wy * 32 + 16 + lw) * 64 + csw]);
            #pragma unroll
            for (int mi = 0; mi < 2; mi++) {
                bf16x8 af = ldg8(&lA[(wx * 32 + mi * 16 + lw) * 64 + csw]);
                acc[mi][0] = MFMA16(af, bf0, acc[mi][0]);
                acc[mi][1] = MFMA16(af, bf1, acc[mi][1]);
            }
        }
        __syncthreads();
    }

    int isf32 = (MODE != 0) ? *flagp : 0;
    #pragma unroll
    for (int ni = 0; ni < 2; ni++) {
        int n = n0 + wy * 32 + ni * 16 + lw;
        float bn = 0.f;
        if (MODE == 2 || ((MODE == 1 || MODE == 3) && kz == 0))
            bn = load_in(bias, boff + n, isf32);
        #pragma unroll
        for (int mi = 0; mi < 2; mi++) {
            #pragma unroll
            for (int r = 0; r < 4; r++) {
                int m = m0 + wx * 32 + mi * 16 + lq * 4 + r;
                float v = acc[mi][ni][r];
                if (MODE == 0) {
                    int b = m >> 10, s = m & 1023;
                    int head = n / 36, d = n - head * 36;
                    size_t bh = (size_t)(b * NH_ + head);
                    if (z == 0)
                        qb[(bh * SEQ_ + s) * DKP_ + d] = f2bf(v * (1.0f / 6.0f));
                    else if (z == 1)
                        kb[(bh * SEQ_ + s) * DKP_ + d] = f2bf(v);
                    else
                        vtb[(bh * DKP_ + d) * SEQ_ + s] = f2bf(v);
                } else if (MODE == 2) {
                    float tt = v + bn;
                    out[(size_t)m * FF_ + n] = f2bf(tt / (1.0f + __expf(-1.702f * tt)));
                } else {
                    // split-K partial: every (m,n,kz) written exactly once
                    pout[(size_t)kz * PSTRIDE_ + (size_t)m * E_ + n] = v + bn;
                }
            }
        }
    }
}

// ---------------------------------------------------------------------------
// Flash attention v8: 64-row q-tiles, 8 waves = 4 q-subtiles x 2 kv-split.
// R7 analysis: the old 16-row tiles were L2-BW-bound -- each block re-read
// all K/V up to its diagonal, ~1.07 GB/layer at ~34.5 TB/s = the 34.5us
// floor. v8 amortizes each K/V chunk over 64 q-rows: the 4 q-waves read the
// same chunk lines (L1/L2 absorbs the duplication; unique traffic ~4x
// lower), kv-split 2 keeps latency hiding, merge is only 2-way. All 4
// q-waves of a block need exactly qt+1 chunks (balanced); waste is only
// diagonal-chunk masking (~4%). Grid 512 = 32 bh x 16 tiles, 2 blocks/CU
// -> whole grid co-resident, zero tail. bh = L&31 XCD affinity.
//
//   Per-wave math (v6, verified): QK^T swapped st = mfma(K, Q) -> lane
//   holds S^T[key][q=lw]; K rows permuted so lane (lw,lq)'s 16 P values
//   are exactly the PV B-fragment: P^T feeds PV with plain packs, no LDS,
//   no bank conflicts. Softmax: 15 lane-local ops + 2 shfl_xor.
//   dm = per-lane ew8[8] (w) x per-chunk sB[4] (h,t).
// ---------------------------------------------------------------------------
__global__ __launch_bounds__(512, 4) void attn_kernel(
    const u16* __restrict__ qb, const u16* __restrict__ kb,
    const u16* __restrict__ vtb, u16* __restrict__ ob)
{
    __shared__ float sm[8][16], sl[8][16], so[8][16][52];
    int lane = threadIdx.x & 63, wave = threadIdx.x >> 6;   // wave 0..7
    int qw = wave >> 1, kw = wave & 1;    // q-subtile / kv-split index
    int lw = lane & 15, lq = lane >> 4;
    int L = blockIdx.x;
    int bh = L & 31;                      // XCD affinity: xcd ~ L%8 = bh%8
    int qt = 15 - (L >> 5);               // 64-row tiles; longest kv first
    int head = bh & 15, b = bh >> 4;
    int q0 = qt * 64 + qw * 16;           // this wave's 16 q-rows

    // Q as B-operand: lane holds Q[q0+lw][lq*8 + j] (pre-scaled by 1/6)
    const u16* qrow = qb + ((size_t)bh * SEQ_ + q0 + lw) * DKP_ + lq * 8;
    bf16x8 qf0 = ldg8(qrow);
    bf16x8 qf1 = ldg8(qrow + 32);

    int tq = q0 >> 8, hq = (q0 >> 4) & 15;
    int qg = q0 + lw;                     // this lane's global q row
    int wq8 = (lq & 1) * 8;               // key w-coord base for this lane
    float ew8[8];
    #pragma unroll
    for (int i = 0; i < 8; i++)
        ew8[i] = __expf((float)abs(lw - (wq8 + i)) * (-1.0f / 33.0f));

    float m_i = -1e30f, l_i = 0.f;
    f32x4 oacc[3];
    #pragma unroll
    for (int c2 = 0; c2 < 3; c2++)
        #pragma unroll
        for (int r = 0; r < 4; r++) oacc[c2][r] = 0.f;

    int kperm = (lw >> 2) * 8 + (lw & 3); // permuted K-row (per load lane)
    const u16* kbh = kb + (size_t)bh * SEQ_ * DKP_;
    const u16* vbh = vtb + (size_t)bh * DKP_ * SEQ_;

    int nch = qt + 1;                     // same for all 4 q-waves
    for (int c = kw; c < nch; c += 2) {
        int kv0 = c * 64;
        bf16x8 kf[4][2], vf[3][2];
        #pragma unroll
        for (int kvh = 0; kvh < 4; kvh++) {
            const u16* kp = kbh +
                (size_t)(kv0 + (kvh >> 1) * 32 + (kvh & 1) * 4 + kperm) * DKP_
                + lq * 8;
            kf[kvh][0] = ldg8(kp);
            kf[kvh][1] = ldg8(kp + 32);
        }
        #pragma unroll
        for (int c2 = 0; c2 < 3; c2++) {
            const u16* vp = vbh + (size_t)(c2 * 16 + lw) * SEQ_ + kv0 + lq * 8;
            vf[c2][0] = ldg8(vp);
            vf[c2][1] = ldg8(vp + 32);
        }
        // S^T tiles: st[kvh][r] = score(key = kv0+(kvh>>1)*32+lq*8+(kvh&1)*4+r,
        //                               q = q0+lw)
        f32x4 st[4];
        #pragma unroll
        for (int kvh = 0; kvh < 4; kvh++) {
            f32x4 tt;
            #pragma unroll
            for (int r = 0; r < 4; r++) tt[r] = 0.f;
            tt = MFMA16(kf[kvh][0], qf0, tt);
            tt = MFMA16(kf[kvh][1], qf1, tt);
            st[kvh] = tt;
        }
        // distance-decay h/t part: chunk spans 4 h values hk0..hk0+3
        int tk = kv0 >> 8, hk0 = (kv0 >> 4) & 15;
        float sB[4];
        #pragma unroll
        for (int i = 0; i < 4; i++)
            sB[i] = __expf((float)(abs(tq - tk) + abs(hq - hk0 - i))
                           * (-1.0f / 33.0f));
        float fh0 = sB[lq >> 1], fh1 = sB[(lq >> 1) + 2];
        float vv[4][4];
        #pragma unroll
        for (int kvh = 0; kvh < 4; kvh++) {
            float fh = (kvh < 2) ? fh0 : fh1;
            #pragma unroll
            for (int r = 0; r < 4; r++)
                vv[kvh][r] = st[kvh][r] * (fh * ew8[(kvh & 1) * 4 + r]);
        }
        if (c == nch - 1) {               // diagonal chunk: causal mask
            #pragma unroll
            for (int kvh = 0; kvh < 4; kvh++) {
                int koff = kv0 + (kvh >> 1) * 32 + lq * 8 + (kvh & 1) * 4;
                #pragma unroll
                for (int r = 0; r < 4; r++)
                    if (koff + r > qg) vv[kvh][r] = -1e30f;
            }
        }
        // online softmax for q=lw: local 16-max + 2 shfls across lq-groups
        float mloc =
            fmaxf(fmaxf(fmaxf(fmaxf(vv[0][0], vv[0][1]), fmaxf(vv[0][2], vv[0][3])),
                        fmaxf(fmaxf(vv[1][0], vv[1][1]), fmaxf(vv[1][2], vv[1][3]))),
                  fmaxf(fmaxf(fmaxf(vv[2][0], vv[2][1]), fmaxf(vv[2][2], vv[2][3])),
                        fmaxf(fmaxf(vv[3][0], vv[3][1]), fmaxf(vv[3][2], vv[3][3]))));
        mloc = fmaxf(mloc, __shfl_xor(mloc, 16));
        mloc = fmaxf(mloc, __shfl_xor(mloc, 32));
        float mn = fmaxf(m_i, mloc);
        float alpha = __expf(m_i - mn);
        m_i = mn;
        float p[4][4];
        float rs = 0.f;
        #pragma unroll
        for (int kvh = 0; kvh < 4; kvh++) {
            #pragma unroll
            for (int r = 0; r < 4; r++) {
                p[kvh][r] = __expf(vv[kvh][r] - mn);
                rs += p[kvh][r];
            }
        }
        rs += __shfl_xor(rs, 16);
        rs += __shfl_xor(rs, 32);
        l_i = l_i * alpha + rs;
        #pragma unroll
        for (int c2 = 0; c2 < 3; c2++)
            #pragma unroll
            for (int r = 0; r < 4; r++) oacc[c2][r] *= alpha;
        // P^T B-fragments fall out directly: pf0 = keys lq*8+0..7,
        // pf1 = keys 32+lq*8+0..7 (for column q=lw)
        bf16x8 pf0, pf1;
        #pragma unroll
        for (int r = 0; r < 4; r++) {
            pf0[r]     = (__bf16)p[0][r];
            pf0[4 + r] = (__bf16)p[1][r];
            pf1[r]     = (__bf16)p[2][r];
            pf1[4 + r] = (__bf16)p[3][r];
        }
        // O^T[d][q] += V^T[d][k] * P^T[k][q]
        #pragma unroll
        for (int c2 = 0; c2 < 3; c2++) {
            oacc[c2] = MFMA16(vf[c2][0], pf0, oacc[c2]);
            oacc[c2] = MFMA16(vf[c2][1], pf1, oacc[c2]);
        }
    }

    // 2-way merge per q-row (kv-split pair). All 4 lq lanes of a given lw
    // carry identical m_i/l_i (post-shfl), so lq==0 writes them. A kw=1
    // wave with no chunks (qt=0) has m=-1e30 -> weight exp(-1e30-M)=0.
    if (lq == 0) { sm[wave][lw] = m_i; sl[wave][lw] = l_i; }
    #pragma unroll
    for (int c2 = 0; c2 < 3; c2++)
        #pragma unroll
        for (int r = 0; r < 4; r++)
            so[wave][lw][c2 * 16 + lq * 4 + r] = oacc[c2][r];
    __syncthreads();
    for (int i = threadIdx.x; i < 64 * DK_; i += 512) {
        int row = i / DK_, col = i - row * DK_;   // row 0..63 within tile
        int qwi = row >> 4, rr = row & 15;
        int w0 = qwi * 2, w1 = w0 + 1;
        float M = fmaxf(sm[w0][rr], sm[w1][rr]);
        float f0 = __expf(sm[w0][rr] - M), f1 = __expf(sm[w1][rr] - M);
        float Lm = f0 * sl[w0][rr] + f1 * sl[w1][rr];
        float O = f0 * so[w0][rr][col] + f1 * so[w1][rr][col];
        ob[((size_t)b * SEQ_ + qt * 64 + row) * E_ + head * DK_ + col]
            = f2bf(O / Lm);
    }
}

// ---------------------------------------------------------------------------
// Output: out = h + sum(p3[0..4)) (last layer's MLP2 partials fused here).
// ---------------------------------------------------------------------------
__global__ void out_kernel(const float* __restrict__ h,
                           const float* __restrict__ p3,
                           void* __restrict__ out,
                           const int* __restrict__ flagp)
{
    int isf32 = *flagp;
    size_t i = (size_t)blockIdx.x * blockDim.x + threadIdx.x;
    float v = h[i] + p3[i] + p3[i + PSTRIDE_] + p3[i + 2 * PSTRIDE_]
            + p3[i + 3 * PSTRIDE_];
    if (isf32) ((float*)out)[i] = v;
    else       ((u16*)out)[i] = f2bf(v);
}

// ---------------------------------------------------------------------------
extern "C" void kernel_launch(void* const* d_in, const int* in_sizes, int n_in,
                              void* d_out, int out_size, void* d_ws,
                              size_t ws_size, hipStream_t stream)
{
    const void* x    = d_in[0];
    const void* sos  = d_in[1];
    const void* pe0  = d_in[2];
    const void* pe1  = d_in[3];
    const void* pe2  = d_in[4];
    const void* ln1s = d_in[5];
    const void* ln1b = d_in[6];
    const void* wq   = d_in[7];
    const void* wk   = d_in[8];
    const void* wv   = d_in[9];
    const void* wo   = d_in[10];
    const void* bo   = d_in[11];
    const void* ln2s = d_in[12];
    const void* ln2b = d_in[13];
    const void* w1   = d_in[14];
    const void* b1   = d_in[15];
    const void* w2   = d_in[16];
    const void* b2   = d_in[17];

    char* ws = (char*)d_ws;
    u16*   qbuf  = (u16*)(ws + 0);          //  4 MB  [B,H,SEQ,64] bf16
    u16*   kbuf  = (u16*)(ws + 4194304);    //  4 MB
    u16*   vtbuf = (u16*)(ws + 8388608);    //  4 MB  [B,H,64,SEQ] bf16
    float* h     = (float*)(ws + 12582912); //  4.7 MB fp32 residual stream
    u16*   y     = (u16*)(ws + 17301504);   //  2.36 MB LN output
    u16*   o     = (u16*)(ws + 19660800);   //  2.36 MB attention output
    u16*   y1    = (u16*)(ws + 22020096);   //  9.4 MB MLP hidden
    u16*   wT    = (u16*)(ws + 31457280);   // 47.8 MB repacked weights
    int*   flag  = (int*)(ws + 79233024);   // dtype flag
    float* p1    = (float*)(ws + 83886080); // 3 x 4.7 MB O-proj split-K partials
    float* p3    = (float*)(ws + 100663296);// 4 x 4.7 MB MLP2 split-K partials
    // (ws_size = 256 MiB per harness poison fill; top use here ~120 MB)

    // zero q/k/vt so DK->DKP padding lanes stay 0 (ws is 0xAA-poisoned)
    hipMemsetAsync(ws, 0, 12582912, stream);
    detect_kernel<<<1, 256, 0, stream>>>((const u16*)x, flag);
    repack_kernel<<<dim3(972, 1, 6), 256, 0, stream>>>(
        wq, wk, wv, wo, w1, w2, wT, flag);
    embed_kernel<<<ROWS_, E_, 0, stream>>>(x, sos, pe0, pe1, pe2, h, flag);

    for (int l = 0; l < NL_; l++) {
        u16* wTl = wT + (size_t)l * 3981312;
        if (l == 0)
            ln_kernel<0><<<512, 256, 0, stream>>>(h, y, nullptr, ln1s, ln1b,
                                                  l * E_, flag);
        else
            ln_kernel<4><<<512, 256, 0, stream>>>(h, y, p3, ln1s, ln1b,
                                                  l * E_, flag);
        gemm_kernel<0, 1><<<dim3(16, 9, 3), 512, 0, stream>>>(
            y, wTl, E_, nullptr, 0, nullptr, nullptr, qbuf, kbuf, vtbuf, flag);
        attn_kernel<<<dim3(512), 512, 0, stream>>>(qbuf, kbuf, vtbuf, o);
        gemm_kernel<1, 3><<<dim3(16, 9, 3), 512, 0, stream>>>(
            o, wTl + 995328, E_, bo, l * E_, p1, nullptr, nullptr, nullptr, nullptr, flag);
        ln_kernel<3><<<512, 256, 0, stream>>>(h, y, p1, ln2s, ln2b,
                                              l * E_, flag);
        gemm_kernel<2, 1><<<dim3(16, 36, 1), 512, 0, stream>>>(
            y, wTl + 1327104, E_, b1, l * FF_, nullptr, y1, nullptr, nullptr, nullptr, flag);
        gemm_kernel<3, 4><<<dim3(16, 9, 4), 512, 0, stream>>>(
            y1, wTl + 2654208, FF_, b2, l * E_, p3, nullptr, nullptr, nullptr, nullptr, flag);
    }
    out_kernel<<<4608, 256, 0, stream>>>(h, p3, d_out, flag);
}

// Round 9
// 748.414 us; speedup vs baseline: 1.0731x; 1.0731x over previous
//
#include <hip/hip_runtime.h>

// ---------------------------------------------------------------------------
// AttentionStack: 6-layer transformer, B=2, SEQ=1024, E=576, H=16, DK=36.
// Inputs/outputs dtype auto-detected (f32 vs bf16) at runtime; internal
// pipeline: bf16 MFMA GEMMs (128x64 tiles, 8-WAVE blocks for TLP, LDS-staged
// 1-phase, split-K via fp32 partial buffers -- no atomics; reduction fused
// into the next LN / output kernel) + fp32 residual stream. Attention:
// swapped-operand flash v6 (R6 measured-best ~34.5us/dispatch): 16-row
// q-tiles, 4-wave kv-split, MANY small blocks (2048) longest-first so the
// CU scheduler can backfill the 16:1 tile imbalance (R8 lesson: 512 big
// blocks = no backfill queue -> idle CUs, 43us).
// ---------------------------------------------------------------------------

#define E_    576
#define SEQ_  1024
#define B_    2
#define NH_   16
#define DK_   36
#define DKP_  64          // DK padded to 64 for MFMA K-steps of 32
#define NL_   6
#define FF_   2304
#define ROWS_ 2048        // B_*SEQ_
#define PSTRIDE_ 1179648  // 2048*576 floats per split-K partial slice

typedef unsigned short u16;
typedef unsigned int u32;
typedef float f32x4 __attribute__((ext_vector_type(4)));
typedef __bf16 bf16x8 __attribute__((ext_vector_type(8)));
typedef __bf16 bf16x4 __attribute__((ext_vector_type(4)));

#define MFMA16(a, b, c) __builtin_amdgcn_mfma_f32_16x16x32_bf16((a), (b), (c), 0, 0, 0)

__device__ __forceinline__ float bf2f(u16 u) {
    return __uint_as_float(((unsigned)u) << 16);
}
__device__ __forceinline__ u16 f2bf(float f) {
    unsigned u = __float_as_uint(f);
    u += 0x7fffu + ((u >> 16) & 1u);   // round-to-nearest-even
    return (u16)(u >> 16);
}
__device__ __forceinline__ float load_in(const void* p, size_t i, int isf32) {
    return isf32 ? ((const float*)p)[i] : bf2f(((const u16*)p)[i]);
}
__device__ __forceinline__ bf16x8 ldg8(const u16* p) {
    uint4 u = *(const uint4*)p;        // 16B aligned by construction
    bf16x8 r;
    __builtin_memcpy(&r, &u, 16);
    return r;
}
// async global->LDS, 16B per lane; LDS dest = wave-uniform base + lane*16
__device__ __forceinline__ void gload_lds16(const u16* g, u16* l) {
    __builtin_amdgcn_global_load_lds(
        (const __attribute__((address_space(1))) unsigned int*)g,
        (__attribute__((address_space(3))) unsigned int*)l, 16, 0, 0);
}

// ---------------------------------------------------------------------------
// Dtype detect: f32 data read as bf16 u16s shows huge magnitudes.
// ---------------------------------------------------------------------------
__global__ void detect_kernel(const u16* __restrict__ x, int* __restrict__ flag)
{
    __shared__ float red[4];
    int lane = threadIdx.x & 63, wave = threadIdx.x >> 6;
    float mx = 0.f;
    for (int i = threadIdx.x; i < 4096; i += 256) {
        float v = fabsf(bf2f(x[i]));
        if (v < 3e38f) mx = fmaxf(mx, v);
    }
    for (int off = 1; off < 64; off <<= 1) mx = fmaxf(mx, __shfl_xor(mx, off));
    if (lane == 0) red[wave] = mx;
    __syncthreads();
    if (threadIdx.x == 0) {
        float m = fmaxf(fmaxf(red[0], red[1]), fmaxf(red[2], red[3]));
        *flag = (m > 1e6f) ? 1 : 0;
    }
}

// ---------------------------------------------------------------------------
// Weight repack v5: W[K][N] -> W^T[N][K] bf16. 64x64 tiles.
// R8 counter read: FETCH_SIZE == bf16 weight bytes -> harness feeds bf16,
// so the hot path was uint2 (8B/lane) loads = Common-mistake #2 (~2x slow).
// v5 bf16 path: thread t -> row=t>>3 (+32), 8-col chunk c8=t&7; uint4 16B
// loads (8 bf16), LDS write 4 consecutive u32 at rr*33+c8*4 (ds_write_b128,
// banks c8*4..+3: conflict-free). f32 path unchanged (was already 16B).
// Store phase unchanged (uint2, verified R7). grid (972, 1, 6), block 256.
// ---------------------------------------------------------------------------
__global__ __launch_bounds__(256) void repack_kernel(
    const void* __restrict__ wq, const void* __restrict__ wk,
    const void* __restrict__ wv, const void* __restrict__ wo,
    const void* __restrict__ w1, const void* __restrict__ w2,
    u16* __restrict__ wT, const int* __restrict__ flagp)
{
    __shared__ u32 tile[64 * 33];           // [row][col-pair], pad 33 words
    int isf32 = *flagp;
    int idx = blockIdx.x, l = blockIdx.z;
    const void* src;
    u16* dst;
    size_t sbase;
    int R, C, cx, ry;
    if (idx < 324) {                        // wq/wk/wv/wo: 576x576, 81 tiles ea
        int t4 = idx / 81, rem = idx - t4 * 81;
        ry = rem / 9; cx = rem % 9; R = 576; C = 576;
        src = (t4 == 0) ? wq : (t4 == 1) ? wk : (t4 == 2) ? wv : wo;
        sbase = (size_t)l * 331776;
        dst = wT + (size_t)l * 3981312 + t4 * 331776;
    } else if (idx < 648) {                 // w1: 576x2304 -> 2304x576
        int rem = idx - 324;
        ry = rem / 36; cx = rem % 36; R = 576; C = 2304;
        src = w1; sbase = (size_t)l * 1327104;
        dst = wT + (size_t)l * 3981312 + 1327104;
    } else {                                // w2: 2304x576 -> 576x2304
        int rem = idx - 648;
        ry = rem / 9; cx = rem % 9; R = 2304; C = 576;
        src = w2; sbase = (size_t)l * 1327104;
        dst = wT + (size_t)l * 3981312 + 2654208;
    }
    int r0 = ry * 64, c0 = cx * 64;
    int t = threadIdx.x;
    if (isf32) {
        // f32 path: thread t covers row (t>>4)+16i, 4-float chunk t&15.
        int chunk = t & 15, row = t >> 4;
        f32x4 vf4[4];
        #pragma unroll
        for (int i = 0; i < 4; i++) {
            int rr = row + i * 16;
            size_t g = sbase + (size_t)(r0 + rr) * C + c0 + chunk * 4;
            vf4[i] = *(const f32x4*)((const float*)src + g);
        }
        #pragma unroll
        for (int i = 0; i < 4; i++) {
            int rr = row + i * 16;
            u32 lo = (u32)f2bf(vf4[i][0]) | ((u32)f2bf(vf4[i][1]) << 16);
            u32 hi = (u32)f2bf(vf4[i][2]) | ((u32)f2bf(vf4[i][3]) << 16);
            tile[rr * 33 + chunk * 2] = lo;
            tile[rr * 33 + chunk * 2 + 1] = hi;
        }
    } else {
        // bf16 path: thread t covers row (t>>3)+32i, 8-col chunk t&7; 16B.
        int c8 = t & 7, row = t >> 3;
        uint4 vq[2];
        #pragma unroll
        for (int i = 0; i < 2; i++) {
            int rr = row + i * 32;
            size_t g = sbase + (size_t)(r0 + rr) * C + c0 + c8 * 8;
            vq[i] = *(const uint4*)((const u16*)src + g);
        }
        #pragma unroll
        for (int i = 0; i < 2; i++) {
            int rr = row + i * 32;
            u32* w = &tile[rr * 33 + c8 * 4];
            w[0] = vq[i].x; w[1] = vq[i].y; w[2] = vq[i].z; w[3] = vq[i].w;
        }
    }
    __syncthreads();
    // store: thread t covers word-pair p2=t&15 of output row nn=(t>>4)+16i.
    int p2 = t & 15, nl = t >> 4;
    #pragma unroll
    for (int i = 0; i < 4; i++) {
        int nn = nl + i * 16;
        int hw = nn >> 1, sh = (nn & 1) * 16;
        u32 wA = tile[(4 * p2)     * 33 + hw];
        u32 wB = tile[(4 * p2 + 1) * 33 + hw];
        u32 wC = tile[(4 * p2 + 2) * 33 + hw];
        u32 wD = tile[(4 * p2 + 3) * 33 + hw];
        u32 a = (wA >> sh) & 0xffffu, b = (wB >> sh) & 0xffffu;
        u32 c = (wC >> sh) & 0xffffu, d = (wD >> sh) & 0xffffu;
        uint2 o;
        o.x = a | (b << 16);
        o.y = c | (d << 16);
        ((uint2*)(dst + (size_t)(c0 + nn) * R + r0))[p2] = o;
    }
}

// ---------------------------------------------------------------------------
// Embed: h = rightshift(x, sos) + concat(pe0[t], pe1[h], pe2[w]); fp32 out.
// ---------------------------------------------------------------------------
__global__ void embed_kernel(
    const void* __restrict__ x, const void* __restrict__ sos,
    const void* __restrict__ pe0, const void* __restrict__ pe1,
    const void* __restrict__ pe2, float* __restrict__ h,
    const int* __restrict__ flagp)
{
    int isf32 = *flagp;
    int row = blockIdx.x;        // b*1024 + s
    int e = threadIdx.x;
    int s = row & 1023;
    float v = (s == 0) ? load_in(sos, e, isf32)
                       : load_in(x, (size_t)(row - 1) * E_ + e, isf32);
    int t = s >> 8, hh = (s >> 4) & 15, ww = s & 15;
    float p = (e < 192) ? load_in(pe0, t * 192 + e, isf32)
            : (e < 384) ? load_in(pe1, hh * 192 + e - 192, isf32)
                        : load_in(pe2, ww * 192 + e - 384, isf32);
    h[(size_t)row * E_ + e] = v + p;
}

// ---------------------------------------------------------------------------
// LayerNorm + fused split-K reduce: h += sum(parts[0..NPART)); y = LN(h).
// NPART=0: plain LN (layer 0 entry). NPART=3: after O-proj. NPART=4: after
// MLP2 (entry of layers 1..5). One wave per row. (R5: replaced ~50M scalar
// f32 atomics/forward with partials + this fused streaming reduce: -74us.)
// ---------------------------------------------------------------------------
template <int NPART>
__global__ __launch_bounds__(256) void ln_kernel(
    float* __restrict__ h, u16* __restrict__ y,
    const float* __restrict__ parts,
    const void* __restrict__ sc, const void* __restrict__ bi,
    int off0, const int* __restrict__ flagp)
{
    int isf32 = *flagp;
    int lane = threadIdx.x & 63, wave = threadIdx.x >> 6;
    int row = blockIdx.x * 4 + wave;
    float* hr = h + (size_t)row * E_;
    float v[9], s = 0.f, sq = 0.f;
    #pragma unroll
    for (int j = 0; j < 9; j++) {
        int e = lane + j * 64;
        float t = hr[e];
        #pragma unroll
        for (int pk = 0; pk < NPART; pk++)
            t += parts[(size_t)pk * PSTRIDE_ + (size_t)row * E_ + e];
        if (NPART > 0) hr[e] = t;   // persist updated residual stream
        v[j] = t;
        s += t;
        sq += t * t;
    }
    for (int off = 1; off < 64; off <<= 1) {
        s += __shfl_xor(s, off);
        sq += __shfl_xor(sq, off);
    }
    float mean = s * (1.0f / E_);
    float var = sq * (1.0f / E_) - mean * mean;
    float r = rsqrtf(var + 1e-5f);
    #pragma unroll
    for (int j = 0; j < 9; j++) {
        int e = lane + j * 64;
        float sce = load_in(sc, off0 + e, isf32);
        float bie = load_in(bi, off0 + e, isf32);
        y[(size_t)row * E_ + e] = f2bf((v[j] - mean) * r * sce + bie);
    }
}

// ---------------------------------------------------------------------------
// GEMM v4 (8-wave TLP): C[m,n] = sum_k A[m,k]*Bt[n,k]. Block tile
// 128(M)x64(N), 512 threads = 8 waves in 4x2 (wx=M-quarter, wy=N-half);
// each wave one 32x32 output (acc[2][2]). (R6: 4->8 waves was -24us; the
// residual GEMM cost is structural per-dispatch overhead, not TLP.)
// MODE 0: QKV (z picks wq/wk/wv; writes q(scaled)/k/vt padded to DKP)
// MODE 1: O-proj partials: pout[kz] = A@woT (+bo on kz==0)   [no atomics]
// MODE 2: MLP1:  y1 = gelu2(A@w1T + b1)  (N stride FF_)
// MODE 3: MLP2 partials: pout[kz] = A@w2T (+b2 on kz==0)     [no atomics]
// ---------------------------------------------------------------------------
template <int MODE, int SPLITK>
__global__ __launch_bounds__(512) void gemm_kernel(
    const u16* __restrict__ A, const u16* __restrict__ BtBase, int K,
    const void* __restrict__ bias, int boff, float* __restrict__ pout,
    u16* __restrict__ out, u16* __restrict__ qb, u16* __restrict__ kb,
    u16* __restrict__ vtb, const int* __restrict__ flagp)
{
    __shared__ u16 lA[8192];     // 128 rows x 64 cols bf16 (16 KB)
    __shared__ u16 lB[4096];     //  64 rows x 64 cols bf16 ( 8 KB)
    int t = threadIdx.x;
    int lane = t & 63, wave = t >> 6;      // wave 0..7
    int lw = lane & 15, lq = lane >> 4;
    int wx = wave >> 1, wy = wave & 1;     // wx 0..3 (M), wy 0..1 (N)
    int m0 = blockIdx.x * 128, n0 = blockIdx.y * 64;
    int z = blockIdx.z / SPLITK, kz = blockIdx.z % SPLITK;
    int Ks = K / SPLITK, kbase = kz * Ks;

    const u16* Bt = BtBase + (MODE == 0 ? (size_t)z * 331776 : 0);
    int rowS = t >> 3;                      // 0..63
    int gc = (t & 7) ^ (rowS & 7);
    const u16* gA = A + (size_t)(m0 + rowS) * K + kbase + gc * 8;
    const u16* gB = Bt + (size_t)(n0 + rowS) * K + kbase + gc * 8;
    size_t rstep = (size_t)64 * K;

    f32x4 acc[2][2];
    for (int mi = 0; mi < 2; mi++)
        for (int ni = 0; ni < 2; ni++)
            for (int r = 0; r < 4; r++) acc[mi][ni][r] = 0.f;

    for (int kc = 0; kc < Ks; kc += 64) {
        gload_lds16(gA + kc,         &lA[t * 8]);        // A rows 0..63
        gload_lds16(gA + rstep + kc, &lA[4096 + t * 8]); // A rows 64..127
        gload_lds16(gB + kc,         &lB[t * 8]);        // B rows 0..63
        __syncthreads();
        #pragma unroll
        for (int ks = 0; ks < 2; ks++) {
            int csw = ((ks * 4 + lq) ^ (lw & 7)) * 8;
            bf16x8 bf0 = ldg8(&lB[(wy * 32 + lw) * 64 + csw]);
            bf16x8 bf1 = ldg8(&lB[(wy * 32 + 16 + lw) * 64 + csw]);
            #pragma unroll
            for (int mi = 0; mi < 2; mi++) {
                bf16x8 af = ldg8(&lA[(wx * 32 + mi * 16 + lw) * 64 + csw]);
                acc[mi][0] = MFMA16(af, bf0, acc[mi][0]);
                acc[mi][1] = MFMA16(af, bf1, acc[mi][1]);
            }
        }
        __syncthreads();
    }

    int isf32 = (MODE != 0) ? *flagp : 0;
    #pragma unroll
    for (int ni = 0; ni < 2; ni++) {
        int n = n0 + wy * 32 + ni * 16 + lw;
        float bn = 0.f;
        if (MODE == 2 || ((MODE == 1 || MODE == 3) && kz == 0))
            bn = load_in(bias, boff + n, isf32);
        #pragma unroll
        for (int mi = 0; mi < 2; mi++) {
            #pragma unroll
            for (int r = 0; r < 4; r++) {
                int m = m0 + wx * 32 + mi * 16 + lq * 4 + r;
                float v = acc[mi][ni][r];
                if (MODE == 0) {
                    int b = m >> 10, s = m & 1023;
                    int head = n / 36, d = n - head * 36;
                    size_t bh = (size_t)(b * NH_ + head);
                    if (z == 0)
                        qb[(bh * SEQ_ + s) * DKP_ + d] = f2bf(v * (1.0f / 6.0f));
                    else if (z == 1)
                        kb[(bh * SEQ_ + s) * DKP_ + d] = f2bf(v);
                    else
                        vtb[(bh * DKP_ + d) * SEQ_ + s] = f2bf(v);
                } else if (MODE == 2) {
                    float tt = v + bn;
                    out[(size_t)m * FF_ + n] = f2bf(tt / (1.0f + __expf(-1.702f * tt)));
                } else {
                    // split-K partial: every (m,n,kz) written exactly once
                    pout[(size_t)kz * PSTRIDE_ + (size_t)m * E_ + n] = v + bn;
                }
            }
        }
    }
}

// ---------------------------------------------------------------------------
// Flash attention v6 (R6 measured-best, reverted verbatim): swapped-operand
// math + 4-wave kv-split. Grid 2048 = 32 bh x 64 q-tiles(16 rows); 4 waves
// split the kv chunks (wave w takes c = w, w+4, ...), flash-decode merge
// via small LDS. bh = L&31 XCD affinity; long tiles first. 2048 small
// blocks = ~8 blocks/CU average -> scheduler backfills the 16:1 tile
// imbalance (R8: 512 big blocks lost this and regressed to 43us).
//
//   QK^T swapped: st = mfma(K, Q) -> lane holds S^T[key][q=lw]; K rows
//   permuted so lane (lw,lq)'s 16 P values are exactly the PV B-fragment
//   (keys lq*8+0..7 / 32+lq*8+0..7): P^T feeds PV with plain packs, no
//   LDS transpose, no bank conflicts. Softmax: 15 lane-local ops + 2
//   shfl_xor. dm = per-lane ew8[8] (w) x per-chunk sB[4] (h,t).
// ---------------------------------------------------------------------------
__global__ __launch_bounds__(256, 4) void attn_kernel(
    const u16* __restrict__ qb, const u16* __restrict__ kb,
    const u16* __restrict__ vtb, u16* __restrict__ ob)
{
    __shared__ float sm[4][16], sl[4][16], so[4][16][52];
    int lane = threadIdx.x & 63, wave = threadIdx.x >> 6;
    int lw = lane & 15, lq = lane >> 4;
    int L = blockIdx.x;
    int bh = L & 31;                      // XCD affinity: xcd ~ L%8 = bh%8
    int qt = 63 - (L >> 5);               // longest kv ranges launch first
    int head = bh & 15, b = bh >> 4;
    int q0 = qt * 16;

    // Q as B-operand: lane holds Q[q0+lw][lq*8 + j] (pre-scaled by 1/6)
    const u16* qrow = qb + ((size_t)bh * SEQ_ + q0 + lw) * DKP_ + lq * 8;
    bf16x8 qf0 = ldg8(qrow);
    bf16x8 qf1 = ldg8(qrow + 32);

    int tq = q0 >> 8, hq = (q0 >> 4) & 15;
    int qg = q0 + lw;                     // this lane's global q row
    int wq8 = (lq & 1) * 8;               // key w-coord base for this lane
    float ew8[8];
    #pragma unroll
    for (int i = 0; i < 8; i++)
        ew8[i] = __expf((float)abs(lw - (wq8 + i)) * (-1.0f / 33.0f));

    float m_i = -1e30f, l_i = 0.f;
    f32x4 oacc[3];
    #pragma unroll
    for (int c2 = 0; c2 < 3; c2++)
        #pragma unroll
        for (int r = 0; r < 4; r++) oacc[c2][r] = 0.f;

    int kperm = (lw >> 2) * 8 + (lw & 3); // permuted K-row (per load lane)
    const u16* kbh = kb + (size_t)bh * SEQ_ * DKP_;
    const u16* vbh = vtb + (size_t)bh * DKP_ * SEQ_;

    int nch = (q0 >> 6) + 1;              // chunks covering keys 0..q0+15
    for (int c = wave; c < nch; c += 4) {
        int kv0 = c * 64;
        bf16x8 kf[4][2], vf[3][2];
        #pragma unroll
        for (int kvh = 0; kvh < 4; kvh++) {
            const u16* kp = kbh +
                (size_t)(kv0 + (kvh >> 1) * 32 + (kvh & 1) * 4 + kperm) * DKP_
                + lq * 8;
            kf[kvh][0] = ldg8(kp);
            kf[kvh][1] = ldg8(kp + 32);
        }
        #pragma unroll
        for (int c2 = 0; c2 < 3; c2++) {
            const u16* vp = vbh + (size_t)(c2 * 16 + lw) * SEQ_ + kv0 + lq * 8;
            vf[c2][0] = ldg8(vp);
            vf[c2][1] = ldg8(vp + 32);
        }
        // S^T tiles: st[kvh][r] = score(key = kv0+(kvh>>1)*32+lq*8+(kvh&1)*4+r,
        //                               q = q0+lw)
        f32x4 st[4];
        #pragma unroll
        for (int kvh = 0; kvh < 4; kvh++) {
            f32x4 tt;
            #pragma unroll
            for (int r = 0; r < 4; r++) tt[r] = 0.f;
            tt = MFMA16(kf[kvh][0], qf0, tt);
            tt = MFMA16(kf[kvh][1], qf1, tt);
            st[kvh] = tt;
        }
        // distance-decay h/t part: chunk spans 4 h values hk0..hk0+3
        int tk = kv0 >> 8, hk0 = (kv0 >> 4) & 15;
        float sB[4];
        #pragma unroll
        for (int i = 0; i < 4; i++)
            sB[i] = __expf((float)(abs(tq - tk) + abs(hq - hk0 - i))
                           * (-1.0f / 33.0f));
        float fh0 = sB[lq >> 1], fh1 = sB[(lq >> 1) + 2];
        float vv[4][4];
        #pragma unroll
        for (int kvh = 0; kvh < 4; kvh++) {
            float fh = (kvh < 2) ? fh0 : fh1;
            #pragma unroll
            for (int r = 0; r < 4; r++)
                vv[kvh][r] = st[kvh][r] * (fh * ew8[(kvh & 1) * 4 + r]);
        }
        if (c == nch - 1) {               // diagonal chunk: causal mask
            #pragma unroll
            for (int kvh = 0; kvh < 4; kvh++) {
                int koff = kv0 + (kvh >> 1) * 32 + lq * 8 + (kvh & 1) * 4;
                #pragma unroll
                for (int r = 0; r < 4; r++)
                    if (koff + r > qg) vv[kvh][r] = -1e30f;
            }
        }
        // online softmax for q=lw: local 16-max + 2 shfls across lq-groups
        float mloc =
            fmaxf(fmaxf(fmaxf(fmaxf(vv[0][0], vv[0][1]), fmaxf(vv[0][2], vv[0][3])),
                        fmaxf(fmaxf(vv[1][0], vv[1][1]), fmaxf(vv[1][2], vv[1][3]))),
                  fmaxf(fmaxf(fmaxf(vv[2][0], vv[2][1]), fmaxf(vv[2][2], vv[2][3])),
                        fmaxf(fmaxf(vv[3][0], vv[3][1]), fmaxf(vv[3][2], vv[3][3]))));
        mloc = fmaxf(mloc, __shfl_xor(mloc, 16));
        mloc = fmaxf(mloc, __shfl_xor(mloc, 32));
        float mn = fmaxf(m_i, mloc);
        float alpha = __expf(m_i - mn);
        m_i = mn;
        float p[4][4];
        float rs = 0.f;
        #pragma unroll
        for (int kvh = 0; kvh < 4; kvh++) {
            #pragma unroll
            for (int r = 0; r < 4; r++) {
                p[kvh][r] = __expf(vv[kvh][r] - mn);
                rs += p[kvh][r];
            }
        }
        rs += __shfl_xor(rs, 16);
        rs += __shfl_xor(rs, 32);
        l_i = l_i * alpha + rs;
        #pragma unroll
        for (int c2 = 0; c2 < 3; c2++)
            #pragma unroll
            for (int r = 0; r < 4; r++) oacc[c2][r] *= alpha;
        // P^T B-fragments fall out directly: pf0 = keys lq*8+0..7,
        // pf1 = keys 32+lq*8+0..7 (for column q=lw)
        bf16x8 pf0, pf1;
        #pragma unroll
        for (int r = 0; r < 4; r++) {
            pf0[r]     = (__bf16)p[0][r];
            pf0[4 + r] = (__bf16)p[1][r];
            pf1[r]     = (__bf16)p[2][r];
            pf1[4 + r] = (__bf16)p[3][r];
        }
        // O^T[d][q] += V^T[d][k] * P^T[k][q]
        #pragma unroll
        for (int c2 = 0; c2 < 3; c2++) {
            oacc[c2] = MFMA16(vf[c2][0], pf0, oacc[c2]);
            oacc[c2] = MFMA16(vf[c2][1], pf1, oacc[c2]);
        }
    }

    // merge 4 waves' partial (m,l,O^T) per q-row. All 4 lq lanes of a given
    // lw carry identical m_i/l_i (post-shfl), so lq==0 writes them.
    if (lq == 0) { sm[wave][lw] = m_i; sl[wave][lw] = l_i; }
    #pragma unroll
    for (int c2 = 0; c2 < 3; c2++)
        #pragma unroll
        for (int r = 0; r < 4; r++)
            so[wave][lw][c2 * 16 + lq * 4 + r] = oacc[c2][r];
    __syncthreads();
    for (int i = threadIdx.x; i < 16 * DK_; i += 256) {
        int row = i / DK_, col = i - row * DK_;
        float M = fmaxf(fmaxf(sm[0][row], sm[1][row]),
                        fmaxf(sm[2][row], sm[3][row]));
        float Lm = 0.f, O = 0.f;
        #pragma unroll
        for (int w = 0; w < 4; w++) {
            float f = __expf(sm[w][row] - M);
            Lm += f * sl[w][row];
            O += f * so[w][row][col];
        }
        ob[((size_t)b * SEQ_ + q0 + row) * E_ + head * DK_ + col] = f2bf(O / Lm);
    }
}

// ---------------------------------------------------------------------------
// Output: out = h + sum(p3[0..4)) (last layer's MLP2 partials fused here).
// ---------------------------------------------------------------------------
__global__ void out_kernel(const float* __restrict__ h,
                           const float* __restrict__ p3,
                           void* __restrict__ out,
                           const int* __restrict__ flagp)
{
    int isf32 = *flagp;
    size_t i = (size_t)blockIdx.x * blockDim.x + threadIdx.x;
    float v = h[i] + p3[i] + p3[i + PSTRIDE_] + p3[i + 2 * PSTRIDE_]
            + p3[i + 3 * PSTRIDE_];
    if (isf32) ((float*)out)[i] = v;
    else       ((u16*)out)[i] = f2bf(v);
}

// ---------------------------------------------------------------------------
extern "C" void kernel_launch(void* const* d_in, const int* in_sizes, int n_in,
                              void* d_out, int out_size, void* d_ws,
                              size_t ws_size, hipStream_t stream)
{
    const void* x    = d_in[0];
    const void* sos  = d_in[1];
    const void* pe0  = d_in[2];
    const void* pe1  = d_in[3];
    const void* pe2  = d_in[4];
    const void* ln1s = d_in[5];
    const void* ln1b = d_in[6];
    const void* wq   = d_in[7];
    const void* wk   = d_in[8];
    const void* wv   = d_in[9];
    const void* wo   = d_in[10];
    const void* bo   = d_in[11];
    const void* ln2s = d_in[12];
    const void* ln2b = d_in[13];
    const void* w1   = d_in[14];
    const void* b1   = d_in[15];
    const void* w2   = d_in[16];
    const void* b2   = d_in[17];

    char* ws = (char*)d_ws;
    u16*   qbuf  = (u16*)(ws + 0);          //  4 MB  [B,H,SEQ,64] bf16
    u16*   kbuf  = (u16*)(ws + 4194304);    //  4 MB
    u16*   vtbuf = (u16*)(ws + 8388608);    //  4 MB  [B,H,64,SEQ] bf16
    float* h     = (float*)(ws + 12582912); //  4.7 MB fp32 residual stream
    u16*   y     = (u16*)(ws + 17301504);   //  2.36 MB LN output
    u16*   o     = (u16*)(ws + 19660800);   //  2.36 MB attention output
    u16*   y1    = (u16*)(ws + 22020096);   //  9.4 MB MLP hidden
    u16*   wT    = (u16*)(ws + 31457280);   // 47.8 MB repacked weights
    int*   flag  = (int*)(ws + 79233024);   // dtype flag
    float* p1    = (float*)(ws + 83886080); // 3 x 4.7 MB O-proj split-K partials
    float* p3    = (float*)(ws + 100663296);// 4 x 4.7 MB MLP2 split-K partials
    // (ws_size = 256 MiB per harness poison fill; top use here ~120 MB)

    // zero q/k/vt so DK->DKP padding lanes stay 0 (ws is 0xAA-poisoned)
    hipMemsetAsync(ws, 0, 12582912, stream);
    detect_kernel<<<1, 256, 0, stream>>>((const u16*)x, flag);
    repack_kernel<<<dim3(972, 1, 6), 256, 0, stream>>>(
        wq, wk, wv, wo, w1, w2, wT, flag);
    embed_kernel<<<ROWS_, E_, 0, stream>>>(x, sos, pe0, pe1, pe2, h, flag);

    for (int l = 0; l < NL_; l++) {
        u16* wTl = wT + (size_t)l * 3981312;
        if (l == 0)
            ln_kernel<0><<<512, 256, 0, stream>>>(h, y, nullptr, ln1s, ln1b,
                                                  l * E_, flag);
        else
            ln_kernel<4><<<512, 256, 0, stream>>>(h, y, p3, ln1s, ln1b,
                                                  l * E_, flag);
        gemm_kernel<0, 1><<<dim3(16, 9, 3), 512, 0, stream>>>(
            y, wTl, E_, nullptr, 0, nullptr, nullptr, qbuf, kbuf, vtbuf, flag);
        attn_kernel<<<dim3(2048), 256, 0, stream>>>(qbuf, kbuf, vtbuf, o);
        gemm_kernel<1, 3><<<dim3(16, 9, 3), 512, 0, stream>>>(
            o, wTl + 995328, E_, bo, l * E_, p1, nullptr, nullptr, nullptr, nullptr, flag);
        ln_kernel<3><<<512, 256, 0, stream>>>(h, y, p1, ln2s, ln2b,
                                              l * E_, flag);
        gemm_kernel<2, 1><<<dim3(16, 36, 1), 512, 0, stream>>>(
            y, wTl + 1327104, E_, b1, l * FF_, nullptr, y1, nullptr, nullptr, nullptr, flag);
        gemm_kernel<3, 4><<<dim3(16, 9, 4), 512, 0, stream>>>(
            y1, wTl + 2654208, FF_, b2, l * E_, p3, nullptr, nullptr, nullptr, nullptr, flag);
    }
    out_kernel<<<4608, 256, 0, stream>>>(h, p3, d_out, flag);
}

// Round 10
// 741.526 us; speedup vs baseline: 1.0830x; 1.0093x over previous
//
#include <hip/hip_runtime.h>

// ---------------------------------------------------------------------------
// AttentionStack: 6-layer transformer, B=2, SEQ=1024, E=576, H=16, DK=36.
// Inputs/outputs dtype auto-detected (f32 vs bf16) at runtime; internal
// pipeline: bf16 MFMA GEMMs (128x64 tiles, 8-wave blocks, LDS-staged
// 1-phase, split-K via fp32 partial buffers; weights repacked into
// PRE-SWIZZLED CONTIGUOUS 8KB TILES so repack stores and GEMM B-stages are
// both fully coalesced) + fp32 residual stream. Attention: swapped-operand
// flash v6 (R6/R9 measured-best): 16-row q-tiles, 4-wave kv-split, 2048
// small blocks longest-first (scheduler backfills the 16:1 imbalance).
// ---------------------------------------------------------------------------

#define E_    576
#define SEQ_  1024
#define B_    2
#define NH_   16
#define DK_   36
#define DKP_  64          // DK padded to 64 for MFMA K-steps of 32
#define NL_   6
#define FF_   2304
#define ROWS_ 2048        // B_*SEQ_
#define PSTRIDE_ 1179648  // 2048*576 floats per split-K partial slice

typedef unsigned short u16;
typedef unsigned int u32;
typedef float f32x4 __attribute__((ext_vector_type(4)));
typedef __bf16 bf16x8 __attribute__((ext_vector_type(8)));
typedef __bf16 bf16x4 __attribute__((ext_vector_type(4)));

#define MFMA16(a, b, c) __builtin_amdgcn_mfma_f32_16x16x32_bf16((a), (b), (c), 0, 0, 0)

__device__ __forceinline__ float bf2f(u16 u) {
    return __uint_as_float(((unsigned)u) << 16);
}
__device__ __forceinline__ u16 f2bf(float f) {
    unsigned u = __float_as_uint(f);
    u += 0x7fffu + ((u >> 16) & 1u);   // round-to-nearest-even
    return (u16)(u >> 16);
}
__device__ __forceinline__ float load_in(const void* p, size_t i, int isf32) {
    return isf32 ? ((const float*)p)[i] : bf2f(((const u16*)p)[i]);
}
__device__ __forceinline__ bf16x8 ldg8(const u16* p) {
    uint4 u = *(const uint4*)p;        // 16B aligned by construction
    bf16x8 r;
    __builtin_memcpy(&r, &u, 16);
    return r;
}
// async global->LDS, 16B per lane; LDS dest = wave-uniform base + lane*16
__device__ __forceinline__ void gload_lds16(const u16* g, u16* l) {
    __builtin_amdgcn_global_load_lds(
        (const __attribute__((address_space(1))) unsigned int*)g,
        (__attribute__((address_space(3))) unsigned int*)l, 16, 0, 0);
}

// ---------------------------------------------------------------------------
// Dtype detect: f32 data read as bf16 u16s shows huge magnitudes.
// ---------------------------------------------------------------------------
__global__ void detect_kernel(const u16* __restrict__ x, int* __restrict__ flag)
{
    __shared__ float red[4];
    int lane = threadIdx.x & 63, wave = threadIdx.x >> 6;
    float mx = 0.f;
    for (int i = threadIdx.x; i < 4096; i += 256) {
        float v = fabsf(bf2f(x[i]));
        if (v < 3e38f) mx = fmaxf(mx, v);
    }
    for (int off = 1; off < 64; off <<= 1) mx = fmaxf(mx, __shfl_xor(mx, off));
    if (lane == 0) red[wave] = mx;
    __syncthreads();
    if (threadIdx.x == 0) {
        float m = fmaxf(fmaxf(red[0], red[1]), fmaxf(red[2], red[3]));
        *flag = (m > 1e6f) ? 1 : 0;
    }
}

// ---------------------------------------------------------------------------
// Weight repack v6: W[K][N] -> TILED W^T: [n_tile][k_tile][64][64] bf16,
// each 8KB tile PRE-SWIZZLED to be the exact LDS image the GEMM stages
// (tile[nn][c8] holds W^T row nn, k-chunk c8^(nn&7)). R9 post-mortem:
// 41us at 2.3 TB/s despite ideal FETCH/WRITE and no latency/VALU limiter
// -> the 128B-segment strided stores (stride 1152/4608B) were the DRAM/L2
// efficiency suspect, plus 4-way LDS conflicts in the store gather (746K
// conflict cycles). v6: store side writes one CONTIGUOUS 8KB extent per
// block (1KB/wave-instr uint4 stores); gather is 2-way (free). GEMM B-side
// becomes a contiguous 8KB stream per K-iter. grid (972, 1, 6), block 256.
// ---------------------------------------------------------------------------
__global__ __launch_bounds__(256) void repack_kernel(
    const void* __restrict__ wq, const void* __restrict__ wk,
    const void* __restrict__ wv, const void* __restrict__ wo,
    const void* __restrict__ w1, const void* __restrict__ w2,
    u16* __restrict__ wT, const int* __restrict__ flagp)
{
    __shared__ u32 tile[64 * 33];           // [row][col-pair], pad 33 words
    int isf32 = *flagp;
    int idx = blockIdx.x, l = blockIdx.z;
    const void* src;
    u16* dst;
    size_t sbase;
    int R, C, cx, ry;
    if (idx < 324) {                        // wq/wk/wv/wo: 576x576, 81 tiles ea
        int t4 = idx / 81, rem = idx - t4 * 81;
        ry = rem / 9; cx = rem % 9; R = 576; C = 576;
        src = (t4 == 0) ? wq : (t4 == 1) ? wk : (t4 == 2) ? wv : wo;
        sbase = (size_t)l * 331776;
        dst = wT + (size_t)l * 3981312 + t4 * 331776;
    } else if (idx < 648) {                 // w1: 576x2304 -> 2304x576
        int rem = idx - 324;
        ry = rem / 36; cx = rem % 36; R = 576; C = 2304;
        src = w1; sbase = (size_t)l * 1327104;
        dst = wT + (size_t)l * 3981312 + 1327104;
    } else {                                // w2: 2304x576 -> 576x2304
        int rem = idx - 648;
        ry = rem / 9; cx = rem % 9; R = 2304; C = 576;
        src = w2; sbase = (size_t)l * 1327104;
        dst = wT + (size_t)l * 3981312 + 2654208;
    }
    int r0 = ry * 64, c0 = cx * 64;
    int t = threadIdx.x;
    if (isf32) {
        // f32 path: thread t covers row (t>>4)+16i, 4-float chunk t&15.
        int chunk = t & 15, row = t >> 4;
        f32x4 vf4[4];
        #pragma unroll
        for (int i = 0; i < 4; i++) {
            int rr = row + i * 16;
            size_t g = sbase + (size_t)(r0 + rr) * C + c0 + chunk * 4;
            vf4[i] = *(const f32x4*)((const float*)src + g);
        }
        #pragma unroll
        for (int i = 0; i < 4; i++) {
            int rr = row + i * 16;
            u32 lo = (u32)f2bf(vf4[i][0]) | ((u32)f2bf(vf4[i][1]) << 16);
            u32 hi = (u32)f2bf(vf4[i][2]) | ((u32)f2bf(vf4[i][3]) << 16);
            tile[rr * 33 + chunk * 2] = lo;
            tile[rr * 33 + chunk * 2 + 1] = hi;
        }
    } else {
        // bf16 path: thread t covers row (t>>3)+32i, 8-col chunk t&7; 16B.
        int c8 = t & 7, row = t >> 3;
        uint4 vq[2];
        #pragma unroll
        for (int i = 0; i < 2; i++) {
            int rr = row + i * 32;
            size_t g = sbase + (size_t)(r0 + rr) * C + c0 + c8 * 8;
            vq[i] = *(const uint4*)((const u16*)src + g);
        }
        #pragma unroll
        for (int i = 0; i < 2; i++) {
            int rr = row + i * 32;
            u32* w = &tile[rr * 33 + c8 * 4];
            w[0] = vq[i].x; w[1] = vq[i].y; w[2] = vq[i].z; w[3] = vq[i].w;
        }
    }
    __syncthreads();
    // store: output tile (n_tile=cx, k_tile=ry) at contiguous 8KB:
    //   tileout[nn][c8pos] (16B units), c8pos = k8 ^ (nn&7)  [pre-swizzle]
    //   holds W^T[c0+nn][r0 + k8*8 .. +7] = W[r0+8*k8+j][c0+nn], j=0..7.
    // Thread t: k8 = t&7, nn = (t>>3) + 32i. LDS gather banks: 2-way (free).
    u16* tbase = dst + ((size_t)cx * (R >> 6) + ry) * 4096;
    int k8 = t & 7, nl = t >> 3;
    #pragma unroll
    for (int i = 0; i < 2; i++) {
        int nn = nl + i * 32;
        int hw = nn >> 1, sh = (nn & 1) * 16;
        u32 v[8];
        #pragma unroll
        for (int j = 0; j < 8; j++)
            v[j] = (tile[(8 * k8 + j) * 33 + hw] >> sh) & 0xffffu;
        uint4 o;
        o.x = v[0] | (v[1] << 16);
        o.y = v[2] | (v[3] << 16);
        o.z = v[4] | (v[5] << 16);
        o.w = v[6] | (v[7] << 16);
        ((uint4*)(tbase + nn * 64))[k8 ^ (nn & 7)] = o;
    }
}

// ---------------------------------------------------------------------------
// Embed: h = rightshift(x, sos) + concat(pe0[t], pe1[h], pe2[w]); fp32 out.
// ---------------------------------------------------------------------------
__global__ void embed_kernel(
    const void* __restrict__ x, const void* __restrict__ sos,
    const void* __restrict__ pe0, const void* __restrict__ pe1,
    const void* __restrict__ pe2, float* __restrict__ h,
    const int* __restrict__ flagp)
{
    int isf32 = *flagp;
    int row = blockIdx.x;        // b*1024 + s
    int e = threadIdx.x;
    int s = row & 1023;
    float v = (s == 0) ? load_in(sos, e, isf32)
                       : load_in(x, (size_t)(row - 1) * E_ + e, isf32);
    int t = s >> 8, hh = (s >> 4) & 15, ww = s & 15;
    float p = (e < 192) ? load_in(pe0, t * 192 + e, isf32)
            : (e < 384) ? load_in(pe1, hh * 192 + e - 192, isf32)
                        : load_in(pe2, ww * 192 + e - 384, isf32);
    h[(size_t)row * E_ + e] = v + p;
}

// ---------------------------------------------------------------------------
// LayerNorm + fused split-K reduce: h += sum(parts[0..NPART)); y = LN(h).
// NPART=0: plain LN (layer 0 entry). NPART=3: after O-proj. NPART=4: after
// MLP2 (entry of layers 1..5). One wave per row. (R5: replaced ~50M scalar
// f32 atomics/forward with partials + this fused streaming reduce: -74us.)
// ---------------------------------------------------------------------------
template <int NPART>
__global__ __launch_bounds__(256) void ln_kernel(
    float* __restrict__ h, u16* __restrict__ y,
    const float* __restrict__ parts,
    const void* __restrict__ sc, const void* __restrict__ bi,
    int off0, const int* __restrict__ flagp)
{
    int isf32 = *flagp;
    int lane = threadIdx.x & 63, wave = threadIdx.x >> 6;
    int row = blockIdx.x * 4 + wave;
    float* hr = h + (size_t)row * E_;
    float v[9], s = 0.f, sq = 0.f;
    #pragma unroll
    for (int j = 0; j < 9; j++) {
        int e = lane + j * 64;
        float t = hr[e];
        #pragma unroll
        for (int pk = 0; pk < NPART; pk++)
            t += parts[(size_t)pk * PSTRIDE_ + (size_t)row * E_ + e];
        if (NPART > 0) hr[e] = t;   // persist updated residual stream
        v[j] = t;
        s += t;
        sq += t * t;
    }
    for (int off = 1; off < 64; off <<= 1) {
        s += __shfl_xor(s, off);
        sq += __shfl_xor(sq, off);
    }
    float mean = s * (1.0f / E_);
    float var = sq * (1.0f / E_) - mean * mean;
    float r = rsqrtf(var + 1e-5f);
    #pragma unroll
    for (int j = 0; j < 9; j++) {
        int e = lane + j * 64;
        float sce = load_in(sc, off0 + e, isf32);
        float bie = load_in(bi, off0 + e, isf32);
        y[(size_t)row * E_ + e] = f2bf((v[j] - mean) * r * sce + bie);
    }
}

// ---------------------------------------------------------------------------
// GEMM v5 (8-wave TLP + tiled-B): C[m,n] = sum_k A[m,k]*Bt[n,k]. Block tile
// 128(M)x64(N), 512 threads = 8 waves in 4x2; each wave one 32x32 output.
// B now comes from the TILED pre-swizzled wT layout: per K-iter the B-tile
// stage is ONE contiguous 8KB stream (tilebase + kc*64 + t*8) -- the tile
// content is byte-identical to what the old swizzled stage produced, so
// the compute loop is unchanged. A-side (activations, row-major) unchanged.
// MODE 0: QKV (z picks wq/wk/wv; writes q(scaled)/k/vt padded to DKP)
// MODE 1: O-proj partials: pout[kz] = A@woT (+bo on kz==0)   [no atomics]
// MODE 2: MLP1:  y1 = gelu2(A@w1T + b1)  (N stride FF_)
// MODE 3: MLP2 partials: pout[kz] = A@w2T (+b2 on kz==0)     [no atomics]
// ---------------------------------------------------------------------------
template <int MODE, int SPLITK>
__global__ __launch_bounds__(512) void gemm_kernel(
    const u16* __restrict__ A, const u16* __restrict__ BtBase, int K,
    const void* __restrict__ bias, int boff, float* __restrict__ pout,
    u16* __restrict__ out, u16* __restrict__ qb, u16* __restrict__ kb,
    u16* __restrict__ vtb, const int* __restrict__ flagp)
{
    __shared__ u16 lA[8192];     // 128 rows x 64 cols bf16 (16 KB)
    __shared__ u16 lB[4096];     //  64 rows x 64 cols bf16 ( 8 KB)
    int t = threadIdx.x;
    int lane = t & 63, wave = t >> 6;      // wave 0..7
    int lw = lane & 15, lq = lane >> 4;
    int wx = wave >> 1, wy = wave & 1;     // wx 0..3 (M), wy 0..1 (N)
    int m0 = blockIdx.x * 128, n0 = blockIdx.y * 64;
    int z = blockIdx.z / SPLITK, kz = blockIdx.z % SPLITK;
    int Ks = K / SPLITK, kbase = kz * Ks;

    const u16* Bt = BtBase + (MODE == 0 ? (size_t)z * 331776 : 0);
    int rowS = t >> 3;                      // 0..63
    int gc = (t & 7) ^ (rowS & 7);
    const u16* gA = A + (size_t)(m0 + rowS) * K + kbase + gc * 8;
    // tiled B: n-tile row base + k offset (kbase, kc are 64-multiples)
    const u16* gB = Bt + ((size_t)(n0 >> 6)) * ((size_t)K << 6)
                  + (size_t)kbase * 64 + (size_t)t * 8;
    size_t rstep = (size_t)64 * K;

    f32x4 acc[2][2];
    for (int mi = 0; mi < 2; mi++)
        for (int ni = 0; ni < 2; ni++)
            for (int r = 0; r < 4; r++) acc[mi][ni][r] = 0.f;

    for (int kc = 0; kc < Ks; kc += 64) {
        gload_lds16(gA + kc,         &lA[t * 8]);        // A rows 0..63
        gload_lds16(gA + rstep + kc, &lA[4096 + t * 8]); // A rows 64..127
        gload_lds16(gB + kc * 64,    &lB[t * 8]);        // B tile (8KB contig)
        __syncthreads();
        #pragma unroll
        for (int ks = 0; ks < 2; ks++) {
            int csw = ((ks * 4 + lq) ^ (lw & 7)) * 8;
            bf16x8 bf0 = ldg8(&lB[(wy * 32 + lw) * 64 + csw]);
            bf16x8 bf1 = ldg8(&lB[(wy * 32 + 16 + lw) * 64 + csw]);
            #pragma unroll
            for (int mi = 0; mi < 2; mi++) {
                bf16x8 af = ldg8(&lA[(wx * 32 + mi * 16 + lw) * 64 + csw]);
                acc[mi][0] = MFMA16(af, bf0, acc[mi][0]);
                acc[mi][1] = MFMA16(af, bf1, acc[mi][1]);
            }
        }
        __syncthreads();
    }

    int isf32 = (MODE != 0) ? *flagp : 0;
    #pragma unroll
    for (int ni = 0; ni < 2; ni++) {
        int n = n0 + wy * 32 + ni * 16 + lw;
        float bn = 0.f;
        if (MODE == 2 || ((MODE == 1 || MODE == 3) && kz == 0))
            bn = load_in(bias, boff + n, isf32);
        #pragma unroll
        for (int mi = 0; mi < 2; mi++) {
            #pragma unroll
            for (int r = 0; r < 4; r++) {
                int m = m0 + wx * 32 + mi * 16 + lq * 4 + r;
                float v = acc[mi][ni][r];
                if (MODE == 0) {
                    int b = m >> 10, s = m & 1023;
                    int head = n / 36, d = n - head * 36;
                    size_t bh = (size_t)(b * NH_ + head);
                    if (z == 0)
                        qb[(bh * SEQ_ + s) * DKP_ + d] = f2bf(v * (1.0f / 6.0f));
                    else if (z == 1)
                        kb[(bh * SEQ_ + s) * DKP_ + d] = f2bf(v);
                    else
                        vtb[(bh * DKP_ + d) * SEQ_ + s] = f2bf(v);
                } else if (MODE == 2) {
                    float tt = v + bn;
                    out[(size_t)m * FF_ + n] = f2bf(tt / (1.0f + __expf(-1.702f * tt)));
                } else {
                    // split-K partial: every (m,n,kz) written exactly once
                    pout[(size_t)kz * PSTRIDE_ + (size_t)m * E_ + n] = v + bn;
                }
            }
        }
    }
}

// ---------------------------------------------------------------------------
// Flash attention v6 (R6/R9 measured-best, unchanged): swapped-operand
// math + 4-wave kv-split. Grid 2048 = 32 bh x 64 q-tiles(16 rows); 4 waves
// split the kv chunks (wave w takes c = w, w+4, ...), flash-decode merge
// via small LDS. bh = L&31 XCD affinity; long tiles first. 2048 small
// blocks = ~8 blocks/CU average -> scheduler backfills the 16:1 tile
// imbalance (R8: 512 big blocks lost this and regressed to 43us).
//
//   QK^T swapped: st = mfma(K, Q) -> lane holds S^T[key][q=lw]; K rows
//   permuted so lane (lw,lq)'s 16 P values are exactly the PV B-fragment
//   (keys lq*8+0..7 / 32+lq*8+0..7): P^T feeds PV with plain packs, no
//   LDS transpose, no bank conflicts. Softmax: 15 lane-local ops + 2
//   shfl_xor. dm = per-lane ew8[8] (w) x per-chunk sB[4] (h,t).
// ---------------------------------------------------------------------------
__global__ __launch_bounds__(256, 4) void attn_kernel(
    const u16* __restrict__ qb, const u16* __restrict__ kb,
    const u16* __restrict__ vtb, u16* __restrict__ ob)
{
    __shared__ float sm[4][16], sl[4][16], so[4][16][52];
    int lane = threadIdx.x & 63, wave = threadIdx.x >> 6;
    int lw = lane & 15, lq = lane >> 4;
    int L = blockIdx.x;
    int bh = L & 31;                      // XCD affinity: xcd ~ L%8 = bh%8
    int qt = 63 - (L >> 5);               // longest kv ranges launch first
    int head = bh & 15, b = bh >> 4;
    int q0 = qt * 16;

    // Q as B-operand: lane holds Q[q0+lw][lq*8 + j] (pre-scaled by 1/6)
    const u16* qrow = qb + ((size_t)bh * SEQ_ + q0 + lw) * DKP_ + lq * 8;
    bf16x8 qf0 = ldg8(qrow);
    bf16x8 qf1 = ldg8(qrow + 32);

    int tq = q0 >> 8, hq = (q0 >> 4) & 15;
    int qg = q0 + lw;                     // this lane's global q row
    int wq8 = (lq & 1) * 8;               // key w-coord base for this lane
    float ew8[8];
    #pragma unroll
    for (int i = 0; i < 8; i++)
        ew8[i] = __expf((float)abs(lw - (wq8 + i)) * (-1.0f / 33.0f));

    float m_i = -1e30f, l_i = 0.f;
    f32x4 oacc[3];
    #pragma unroll
    for (int c2 = 0; c2 < 3; c2++)
        #pragma unroll
        for (int r = 0; r < 4; r++) oacc[c2][r] = 0.f;

    int kperm = (lw >> 2) * 8 + (lw & 3); // permuted K-row (per load lane)
    const u16* kbh = kb + (size_t)bh * SEQ_ * DKP_;
    const u16* vbh = vtb + (size_t)bh * DKP_ * SEQ_;

    int nch = (q0 >> 6) + 1;              // chunks covering keys 0..q0+15
    for (int c = wave; c < nch; c += 4) {
        int kv0 = c * 64;
        bf16x8 kf[4][2], vf[3][2];
        #pragma unroll
        for (int kvh = 0; kvh < 4; kvh++) {
            const u16* kp = kbh +
                (size_t)(kv0 + (kvh >> 1) * 32 + (kvh & 1) * 4 + kperm) * DKP_
                + lq * 8;
            kf[kvh][0] = ldg8(kp);
            kf[kvh][1] = ldg8(kp + 32);
        }
        #pragma unroll
        for (int c2 = 0; c2 < 3; c2++) {
            const u16* vp = vbh + (size_t)(c2 * 16 + lw) * SEQ_ + kv0 + lq * 8;
            vf[c2][0] = ldg8(vp);
            vf[c2][1] = ldg8(vp + 32);
        }
        // S^T tiles: st[kvh][r] = score(key = kv0+(kvh>>1)*32+lq*8+(kvh&1)*4+r,
        //                               q = q0+lw)
        f32x4 st[4];
        #pragma unroll
        for (int kvh = 0; kvh < 4; kvh++) {
            f32x4 tt;
            #pragma unroll
            for (int r = 0; r < 4; r++) tt[r] = 0.f;
            tt = MFMA16(kf[kvh][0], qf0, tt);
            tt = MFMA16(kf[kvh][1], qf1, tt);
            st[kvh] = tt;
        }
        // distance-decay h/t part: chunk spans 4 h values hk0..hk0+3
        int tk = kv0 >> 8, hk0 = (kv0 >> 4) & 15;
        float sB[4];
        #pragma unroll
        for (int i = 0; i < 4; i++)
            sB[i] = __expf((float)(abs(tq - tk) + abs(hq - hk0 - i))
                           * (-1.0f / 33.0f));
        float fh0 = sB[lq >> 1], fh1 = sB[(lq >> 1) + 2];
        float vv[4][4];
        #pragma unroll
        for (int kvh = 0; kvh < 4; kvh++) {
            float fh = (kvh < 2) ? fh0 : fh1;
            #pragma unroll
            for (int r = 0; r < 4; r++)
                vv[kvh][r] = st[kvh][r] * (fh * ew8[(kvh & 1) * 4 + r]);
        }
        if (c == nch - 1) {               // diagonal chunk: causal mask
            #pragma unroll
            for (int kvh = 0; kvh < 4; kvh++) {
                int koff = kv0 + (kvh >> 1) * 32 + lq * 8 + (kvh & 1) * 4;
                #pragma unroll
                for (int r = 0; r < 4; r++)
                    if (koff + r > qg) vv[kvh][r] = -1e30f;
            }
        }
        // online softmax for q=lw: local 16-max + 2 shfls across lq-groups
        float mloc =
            fmaxf(fmaxf(fmaxf(fmaxf(vv[0][0], vv[0][1]), fmaxf(vv[0][2], vv[0][3])),
                        fmaxf(fmaxf(vv[1][0], vv[1][1]), fmaxf(vv[1][2], vv[1][3]))),
                  fmaxf(fmaxf(fmaxf(vv[2][0], vv[2][1]), fmaxf(vv[2][2], vv[2][3])),
                        fmaxf(fmaxf(vv[3][0], vv[3][1]), fmaxf(vv[3][2], vv[3][3]))));
        mloc = fmaxf(mloc, __shfl_xor(mloc, 16));
        mloc = fmaxf(mloc, __shfl_xor(mloc, 32));
        float mn = fmaxf(m_i, mloc);
        float alpha = __expf(m_i - mn);
        m_i = mn;
        float p[4][4];
        float rs = 0.f;
        #pragma unroll
        for (int kvh = 0; kvh < 4; kvh++) {
            #pragma unroll
            for (int r = 0; r < 4; r++) {
                p[kvh][r] = __expf(vv[kvh][r] - mn);
                rs += p[kvh][r];
            }
        }
        rs += __shfl_xor(rs, 16);
        rs += __shfl_xor(rs, 32);
        l_i = l_i * alpha + rs;
        #pragma unroll
        for (int c2 = 0; c2 < 3; c2++)
            #pragma unroll
            for (int r = 0; r < 4; r++) oacc[c2][r] *= alpha;
        // P^T B-fragments fall out directly: pf0 = keys lq*8+0..7,
        // pf1 = keys 32+lq*8+0..7 (for column q=lw)
        bf16x8 pf0, pf1;
        #pragma unroll
        for (int r = 0; r < 4; r++) {
            pf0[r]     = (__bf16)p[0][r];
            pf0[4 + r] = (__bf16)p[1][r];
            pf1[r]     = (__bf16)p[2][r];
            pf1[4 + r] = (__bf16)p[3][r];
        }
        // O^T[d][q] += V^T[d][k] * P^T[k][q]
        #pragma unroll
        for (int c2 = 0; c2 < 3; c2++) {
            oacc[c2] = MFMA16(vf[c2][0], pf0, oacc[c2]);
            oacc[c2] = MFMA16(vf[c2][1], pf1, oacc[c2]);
        }
    }

    // merge 4 waves' partial (m,l,O^T) per q-row. All 4 lq lanes of a given
    // lw carry identical m_i/l_i (post-shfl), so lq==0 writes them.
    if (lq == 0) { sm[wave][lw] = m_i; sl[wave][lw] = l_i; }
    #pragma unroll
    for (int c2 = 0; c2 < 3; c2++)
        #pragma unroll
        for (int r = 0; r < 4; r++)
            so[wave][lw][c2 * 16 + lq * 4 + r] = oacc[c2][r];
    __syncthreads();
    for (int i = threadIdx.x; i < 16 * DK_; i += 256) {
        int row = i / DK_, col = i - row * DK_;
        float M = fmaxf(fmaxf(sm[0][row], sm[1][row]),
                        fmaxf(sm[2][row], sm[3][row]));
        float Lm = 0.f, O = 0.f;
        #pragma unroll
        for (int w = 0; w < 4; w++) {
            float f = __expf(sm[w][row] - M);
            Lm += f * sl[w][row];
            O += f * so[w][row][col];
        }
        ob[((size_t)b * SEQ_ + q0 + row) * E_ + head * DK_ + col] = f2bf(O / Lm);
    }
}

// ---------------------------------------------------------------------------
// Output: out = h + sum(p3[0..4)) (last layer's MLP2 partials fused here).
// ---------------------------------------------------------------------------
__global__ void out_kernel(const float* __restrict__ h,
                           const float* __restrict__ p3,
                           void* __restrict__ out,
                           const int* __restrict__ flagp)
{
    int isf32 = *flagp;
    size_t i = (size_t)blockIdx.x * blockDim.x + threadIdx.x;
    float v = h[i] + p3[i] + p3[i + PSTRIDE_] + p3[i + 2 * PSTRIDE_]
            + p3[i + 3 * PSTRIDE_];
    if (isf32) ((float*)out)[i] = v;
    else       ((u16*)out)[i] = f2bf(v);
}

// ---------------------------------------------------------------------------
extern "C" void kernel_launch(void* const* d_in, const int* in_sizes, int n_in,
                              void* d_out, int out_size, void* d_ws,
                              size_t ws_size, hipStream_t stream)
{
    const void* x    = d_in[0];
    const void* sos  = d_in[1];
    const void* pe0  = d_in[2];
    const void* pe1  = d_in[3];
    const void* pe2  = d_in[4];
    const void* ln1s = d_in[5];
    const void* ln1b = d_in[6];
    const void* wq   = d_in[7];
    const void* wk   = d_in[8];
    const void* wv   = d_in[9];
    const void* wo   = d_in[10];
    const void* bo   = d_in[11];
    const void* ln2s = d_in[12];
    const void* ln2b = d_in[13];
    const void* w1   = d_in[14];
    const void* b1   = d_in[15];
    const void* w2   = d_in[16];
    const void* b2   = d_in[17];

    char* ws = (char*)d_ws;
    u16*   qbuf  = (u16*)(ws + 0);          //  4 MB  [B,H,SEQ,64] bf16
    u16*   kbuf  = (u16*)(ws + 4194304);    //  4 MB
    u16*   vtbuf = (u16*)(ws + 8388608);    //  4 MB  [B,H,64,SEQ] bf16
    float* h     = (float*)(ws + 12582912); //  4.7 MB fp32 residual stream
    u16*   y     = (u16*)(ws + 17301504);   //  2.36 MB LN output
    u16*   o     = (u16*)(ws + 19660800);   //  2.36 MB attention output
    u16*   y1    = (u16*)(ws + 22020096);   //  9.4 MB MLP hidden
    u16*   wT    = (u16*)(ws + 31457280);   // 47.8 MB repacked weights (tiled)
    int*   flag  = (int*)(ws + 79233024);   // dtype flag
    float* p1    = (float*)(ws + 83886080); // 3 x 4.7 MB O-proj split-K partials
    float* p3    = (float*)(ws + 100663296);// 4 x 4.7 MB MLP2 split-K partials
    // (ws_size = 256 MiB per harness poison fill; top use here ~120 MB)

    // zero q/k/vt so DK->DKP padding lanes stay 0 (ws is 0xAA-poisoned)
    hipMemsetAsync(ws, 0, 12582912, stream);
    detect_kernel<<<1, 256, 0, stream>>>((const u16*)x, flag);
    repack_kernel<<<dim3(972, 1, 6), 256, 0, stream>>>(
        wq, wk, wv, wo, w1, w2, wT, flag);
    embed_kernel<<<ROWS_, E_, 0, stream>>>(x, sos, pe0, pe1, pe2, h, flag);

    for (int l = 0; l < NL_; l++) {
        u16* wTl = wT + (size_t)l * 3981312;
        if (l == 0)
            ln_kernel<0><<<512, 256, 0, stream>>>(h, y, nullptr, ln1s, ln1b,
                                                  l * E_, flag);
        else
            ln_kernel<4><<<512, 256, 0, stream>>>(h, y, p3, ln1s, ln1b,
                                                  l * E_, flag);
        gemm_kernel<0, 1><<<dim3(16, 9, 3), 512, 0, stream>>>(
            y, wTl, E_, nullptr, 0, nullptr, nullptr, qbuf, kbuf, vtbuf, flag);
        attn_kernel<<<dim3(2048), 256, 0, stream>>>(qbuf, kbuf, vtbuf, o);
        gemm_kernel<1, 3><<<dim3(16, 9, 3), 512, 0, stream>>>(
            o, wTl + 995328, E_, bo, l * E_, p1, nullptr, nullptr, nullptr, nullptr, flag);
        ln_kernel<3><<<512, 256, 0, stream>>>(h, y, p1, ln2s, ln2b,
                                              l * E_, flag);
        gemm_kernel<2, 1><<<dim3(16, 36, 1), 512, 0, stream>>>(
            y, wTl + 1327104, E_, b1, l * FF_, nullptr, y1, nullptr, nullptr, nullptr, flag);
        gemm_kernel<3, 4><<<dim3(16, 9, 4), 512, 0, stream>>>(
            y1, wTl + 2654208, FF_, b2, l * E_, p3, nullptr, nullptr, nullptr, nullptr, flag);
    }
    out_kernel<<<4608, 256, 0, stream>>>(h, p3, d_out, flag);
}

// Round 11
// 698.829 us; speedup vs baseline: 1.1492x; 1.0611x over previous
//
#include <hip/hip_runtime.h>

// ---------------------------------------------------------------------------
// AttentionStack: 6-layer transformer, B=2, SEQ=1024, E=576, H=16, DK=36.
// Inputs/outputs dtype auto-detected (f32 vs bf16) at runtime; internal
// pipeline: bf16 MFMA GEMMs (128x64 tiles, 8-wave blocks, LDS-staged
// 1-phase, split-K via fp32 partial buffers, weights in pre-swizzled
// contiguous 8KB tiles) + fp32 residual stream. Attention v7-32: swapped-
// operand flash on the 32x32x16 MFMA shape -- each wave covers 32 q-rows
// per chunk (2x v6), halving per-row load traffic and instructions; K-row
// bit2<->3 swap permutation makes P^T feed PV with zero shuffles.
// ---------------------------------------------------------------------------

#define E_    576
#define SEQ_  1024
#define B_    2
#define NH_   16
#define DK_   36
#define DKP_  64          // DK padded to 64 for MFMA K-steps
#define NL_   6
#define FF_   2304
#define ROWS_ 2048        // B_*SEQ_
#define PSTRIDE_ 1179648  // 2048*576 floats per split-K partial slice

typedef unsigned short u16;
typedef unsigned int u32;
typedef float f32x4 __attribute__((ext_vector_type(4)));
typedef float f32x16 __attribute__((ext_vector_type(16)));
typedef __bf16 bf16x8 __attribute__((ext_vector_type(8)));
typedef __bf16 bf16x4 __attribute__((ext_vector_type(4)));

#define MFMA16(a, b, c) __builtin_amdgcn_mfma_f32_16x16x32_bf16((a), (b), (c), 0, 0, 0)
#define MFMA32(a, b, c) __builtin_amdgcn_mfma_f32_32x32x16_bf16((a), (b), (c), 0, 0, 0)

__device__ __forceinline__ float bf2f(u16 u) {
    return __uint_as_float(((unsigned)u) << 16);
}
__device__ __forceinline__ u16 f2bf(float f) {
    unsigned u = __float_as_uint(f);
    u += 0x7fffu + ((u >> 16) & 1u);   // round-to-nearest-even
    return (u16)(u >> 16);
}
__device__ __forceinline__ float load_in(const void* p, size_t i, int isf32) {
    return isf32 ? ((const float*)p)[i] : bf2f(((const u16*)p)[i]);
}
__device__ __forceinline__ bf16x8 ldg8(const u16* p) {
    uint4 u = *(const uint4*)p;        // 16B aligned by construction
    bf16x8 r;
    __builtin_memcpy(&r, &u, 16);
    return r;
}
// async global->LDS, 16B per lane; LDS dest = wave-uniform base + lane*16
__device__ __forceinline__ void gload_lds16(const u16* g, u16* l) {
    __builtin_amdgcn_global_load_lds(
        (const __attribute__((address_space(1))) unsigned int*)g,
        (__attribute__((address_space(3))) unsigned int*)l, 16, 0, 0);
}

// ---------------------------------------------------------------------------
// Dtype detect: f32 data read as bf16 u16s shows huge magnitudes.
// ---------------------------------------------------------------------------
__global__ void detect_kernel(const u16* __restrict__ x, int* __restrict__ flag)
{
    __shared__ float red[4];
    int lane = threadIdx.x & 63, wave = threadIdx.x >> 6;
    float mx = 0.f;
    for (int i = threadIdx.x; i < 4096; i += 256) {
        float v = fabsf(bf2f(x[i]));
        if (v < 3e38f) mx = fmaxf(mx, v);
    }
    for (int off = 1; off < 64; off <<= 1) mx = fmaxf(mx, __shfl_xor(mx, off));
    if (lane == 0) red[wave] = mx;
    __syncthreads();
    if (threadIdx.x == 0) {
        float m = fmaxf(fmaxf(red[0], red[1]), fmaxf(red[2], red[3]));
        *flag = (m > 1e6f) ? 1 : 0;
    }
}

// ---------------------------------------------------------------------------
// Weight repack v6 (R10 verified): W[K][N] -> TILED W^T [n_tile][k_tile]
// [64][64] bf16, each 8KB tile pre-swizzled as the GEMM's LDS image.
// Contiguous 8KB store extents; 2-way (free) LDS gather. grid (972,1,6).
// ---------------------------------------------------------------------------
__global__ __launch_bounds__(256) void repack_kernel(
    const void* __restrict__ wq, const void* __restrict__ wk,
    const void* __restrict__ wv, const void* __restrict__ wo,
    const void* __restrict__ w1, const void* __restrict__ w2,
    u16* __restrict__ wT, const int* __restrict__ flagp)
{
    __shared__ u32 tile[64 * 33];           // [row][col-pair], pad 33 words
    int isf32 = *flagp;
    int idx = blockIdx.x, l = blockIdx.z;
    const void* src;
    u16* dst;
    size_t sbase;
    int R, C, cx, ry;
    if (idx < 324) {                        // wq/wk/wv/wo: 576x576, 81 tiles ea
        int t4 = idx / 81, rem = idx - t4 * 81;
        ry = rem / 9; cx = rem % 9; R = 576; C = 576;
        src = (t4 == 0) ? wq : (t4 == 1) ? wk : (t4 == 2) ? wv : wo;
        sbase = (size_t)l * 331776;
        dst = wT + (size_t)l * 3981312 + t4 * 331776;
    } else if (idx < 648) {                 // w1: 576x2304 -> 2304x576
        int rem = idx - 324;
        ry = rem / 36; cx = rem % 36; R = 576; C = 2304;
        src = w1; sbase = (size_t)l * 1327104;
        dst = wT + (size_t)l * 3981312 + 1327104;
    } else {                                // w2: 2304x576 -> 576x2304
        int rem = idx - 648;
        ry = rem / 9; cx = rem % 9; R = 2304; C = 576;
        src = w2; sbase = (size_t)l * 1327104;
        dst = wT + (size_t)l * 3981312 + 2654208;
    }
    int r0 = ry * 64, c0 = cx * 64;
    int t = threadIdx.x;
    if (isf32) {
        int chunk = t & 15, row = t >> 4;
        f32x4 vf4[4];
        #pragma unroll
        for (int i = 0; i < 4; i++) {
            int rr = row + i * 16;
            size_t g = sbase + (size_t)(r0 + rr) * C + c0 + chunk * 4;
            vf4[i] = *(const f32x4*)((const float*)src + g);
        }
        #pragma unroll
        for (int i = 0; i < 4; i++) {
            int rr = row + i * 16;
            u32 lo = (u32)f2bf(vf4[i][0]) | ((u32)f2bf(vf4[i][1]) << 16);
            u32 hi = (u32)f2bf(vf4[i][2]) | ((u32)f2bf(vf4[i][3]) << 16);
            tile[rr * 33 + chunk * 2] = lo;
            tile[rr * 33 + chunk * 2 + 1] = hi;
        }
    } else {
        int c8 = t & 7, row = t >> 3;
        uint4 vq[2];
        #pragma unroll
        for (int i = 0; i < 2; i++) {
            int rr = row + i * 32;
            size_t g = sbase + (size_t)(r0 + rr) * C + c0 + c8 * 8;
            vq[i] = *(const uint4*)((const u16*)src + g);
        }
        #pragma unroll
        for (int i = 0; i < 2; i++) {
            int rr = row + i * 32;
            u32* w = &tile[rr * 33 + c8 * 4];
            w[0] = vq[i].x; w[1] = vq[i].y; w[2] = vq[i].z; w[3] = vq[i].w;
        }
    }
    __syncthreads();
    u16* tbase = dst + ((size_t)cx * (R >> 6) + ry) * 4096;
    int k8 = t & 7, nl = t >> 3;
    #pragma unroll
    for (int i = 0; i < 2; i++) {
        int nn = nl + i * 32;
        int hw = nn >> 1, sh = (nn & 1) * 16;
        u32 v[8];
        #pragma unroll
        for (int j = 0; j < 8; j++)
            v[j] = (tile[(8 * k8 + j) * 33 + hw] >> sh) & 0xffffu;
        uint4 o;
        o.x = v[0] | (v[1] << 16);
        o.y = v[2] | (v[3] << 16);
        o.z = v[4] | (v[5] << 16);
        o.w = v[6] | (v[7] << 16);
        ((uint4*)(tbase + nn * 64))[k8 ^ (nn & 7)] = o;
    }
}

// ---------------------------------------------------------------------------
// Embed: h = rightshift(x, sos) + concat(pe0[t], pe1[h], pe2[w]); fp32 out.
// ---------------------------------------------------------------------------
__global__ void embed_kernel(
    const void* __restrict__ x, const void* __restrict__ sos,
    const void* __restrict__ pe0, const void* __restrict__ pe1,
    const void* __restrict__ pe2, float* __restrict__ h,
    const int* __restrict__ flagp)
{
    int isf32 = *flagp;
    int row = blockIdx.x;        // b*1024 + s
    int e = threadIdx.x;
    int s = row & 1023;
    float v = (s == 0) ? load_in(sos, e, isf32)
                       : load_in(x, (size_t)(row - 1) * E_ + e, isf32);
    int t = s >> 8, hh = (s >> 4) & 15, ww = s & 15;
    float p = (e < 192) ? load_in(pe0, t * 192 + e, isf32)
            : (e < 384) ? load_in(pe1, hh * 192 + e - 192, isf32)
                        : load_in(pe2, ww * 192 + e - 384, isf32);
    h[(size_t)row * E_ + e] = v + p;
}

// ---------------------------------------------------------------------------
// LayerNorm + fused split-K reduce: h += sum(parts[0..NPART)); y = LN(h).
// NPART=0: plain LN (layer 0 entry). NPART=3: after O-proj. NPART=4: after
// MLP2 (entry of layers 1..5). One wave per row. (R5: -74us vs atomics.)
// ---------------------------------------------------------------------------
template <int NPART>
__global__ __launch_bounds__(256) void ln_kernel(
    float* __restrict__ h, u16* __restrict__ y,
    const float* __restrict__ parts,
    const void* __restrict__ sc, const void* __restrict__ bi,
    int off0, const int* __restrict__ flagp)
{
    int isf32 = *flagp;
    int lane = threadIdx.x & 63, wave = threadIdx.x >> 6;
    int row = blockIdx.x * 4 + wave;
    float* hr = h + (size_t)row * E_;
    float v[9], s = 0.f, sq = 0.f;
    #pragma unroll
    for (int j = 0; j < 9; j++) {
        int e = lane + j * 64;
        float t = hr[e];
        #pragma unroll
        for (int pk = 0; pk < NPART; pk++)
            t += parts[(size_t)pk * PSTRIDE_ + (size_t)row * E_ + e];
        if (NPART > 0) hr[e] = t;   // persist updated residual stream
        v[j] = t;
        s += t;
        sq += t * t;
    }
    for (int off = 1; off < 64; off <<= 1) {
        s += __shfl_xor(s, off);
        sq += __shfl_xor(sq, off);
    }
    float mean = s * (1.0f / E_);
    float var = sq * (1.0f / E_) - mean * mean;
    float r = rsqrtf(var + 1e-5f);
    #pragma unroll
    for (int j = 0; j < 9; j++) {
        int e = lane + j * 64;
        float sce = load_in(sc, off0 + e, isf32);
        float bie = load_in(bi, off0 + e, isf32);
        y[(size_t)row * E_ + e] = f2bf((v[j] - mean) * r * sce + bie);
    }
}

// ---------------------------------------------------------------------------
// GEMM v5 (8-wave TLP + tiled-B, R10 verified): C[m,n] = sum_k A[m,k]*Bt[n,k].
// Block tile 128(M)x64(N), 512 threads = 8 waves in 4x2; wave = 32x32 out.
// B staged as ONE contiguous 8KB stream from the tiled wT layout.
// MODE 0: QKV (z picks wq/wk/wv; writes q(scaled)/k/vt padded to DKP)
// MODE 1: O-proj partials: pout[kz] = A@woT (+bo on kz==0)   [no atomics]
// MODE 2: MLP1:  y1 = gelu2(A@w1T + b1)  (N stride FF_)
// MODE 3: MLP2 partials: pout[kz] = A@w2T (+b2 on kz==0)     [no atomics]
// ---------------------------------------------------------------------------
template <int MODE, int SPLITK>
__global__ __launch_bounds__(512) void gemm_kernel(
    const u16* __restrict__ A, const u16* __restrict__ BtBase, int K,
    const void* __restrict__ bias, int boff, float* __restrict__ pout,
    u16* __restrict__ out, u16* __restrict__ qb, u16* __restrict__ kb,
    u16* __restrict__ vtb, const int* __restrict__ flagp)
{
    __shared__ u16 lA[8192];     // 128 rows x 64 cols bf16 (16 KB)
    __shared__ u16 lB[4096];     //  64 rows x 64 cols bf16 ( 8 KB)
    int t = threadIdx.x;
    int lane = t & 63, wave = t >> 6;      // wave 0..7
    int lw = lane & 15, lq = lane >> 4;
    int wx = wave >> 1, wy = wave & 1;     // wx 0..3 (M), wy 0..1 (N)
    int m0 = blockIdx.x * 128, n0 = blockIdx.y * 64;
    int z = blockIdx.z / SPLITK, kz = blockIdx.z % SPLITK;
    int Ks = K / SPLITK, kbase = kz * Ks;

    const u16* Bt = BtBase + (MODE == 0 ? (size_t)z * 331776 : 0);
    int rowS = t >> 3;                      // 0..63
    int gc = (t & 7) ^ (rowS & 7);
    const u16* gA = A + (size_t)(m0 + rowS) * K + kbase + gc * 8;
    const u16* gB = Bt + ((size_t)(n0 >> 6)) * ((size_t)K << 6)
                  + (size_t)kbase * 64 + (size_t)t * 8;
    size_t rstep = (size_t)64 * K;

    f32x4 acc[2][2];
    for (int mi = 0; mi < 2; mi++)
        for (int ni = 0; ni < 2; ni++)
            for (int r = 0; r < 4; r++) acc[mi][ni][r] = 0.f;

    for (int kc = 0; kc < Ks; kc += 64) {
        gload_lds16(gA + kc,         &lA[t * 8]);        // A rows 0..63
        gload_lds16(gA + rstep + kc, &lA[4096 + t * 8]); // A rows 64..127
        gload_lds16(gB + kc * 64,    &lB[t * 8]);        // B tile (8KB contig)
        __syncthreads();
        #pragma unroll
        for (int ks = 0; ks < 2; ks++) {
            int csw = ((ks * 4 + lq) ^ (lw & 7)) * 8;
            bf16x8 bf0 = ldg8(&lB[(wy * 32 + lw) * 64 + csw]);
            bf16x8 bf1 = ldg8(&lB[(wy * 32 + 16 + lw) * 64 + csw]);
            #pragma unroll
            for (int mi = 0; mi < 2; mi++) {
                bf16x8 af = ldg8(&lA[(wx * 32 + mi * 16 + lw) * 64 + csw]);
                acc[mi][0] = MFMA16(af, bf0, acc[mi][0]);
                acc[mi][1] = MFMA16(af, bf1, acc[mi][1]);
            }
        }
        __syncthreads();
    }

    int isf32 = (MODE != 0) ? *flagp : 0;
    #pragma unroll
    for (int ni = 0; ni < 2; ni++) {
        int n = n0 + wy * 32 + ni * 16 + lw;
        float bn = 0.f;
        if (MODE == 2 || ((MODE == 1 || MODE == 3) && kz == 0))
            bn = load_in(bias, boff + n, isf32);
        #pragma unroll
        for (int mi = 0; mi < 2; mi++) {
            #pragma unroll
            for (int r = 0; r < 4; r++) {
                int m = m0 + wx * 32 + mi * 16 + lq * 4 + r;
                float v = acc[mi][ni][r];
                if (MODE == 0) {
                    int b = m >> 10, s = m & 1023;
                    int head = n / 36, d = n - head * 36;
                    size_t bh = (size_t)(b * NH_ + head);
                    if (z == 0)
                        qb[(bh * SEQ_ + s) * DKP_ + d] = f2bf(v * (1.0f / 6.0f));
                    else if (z == 1)
                        kb[(bh * SEQ_ + s) * DKP_ + d] = f2bf(v);
                    else
                        vtb[(bh * DKP_ + d) * SEQ_ + s] = f2bf(v);
                } else if (MODE == 2) {
                    float tt = v + bn;
                    out[(size_t)m * FF_ + n] = f2bf(tt / (1.0f + __expf(-1.702f * tt)));
                } else {
                    // split-K partial: every (m,n,kz) written exactly once
                    pout[(size_t)kz * PSTRIDE_ + (size_t)m * E_ + n] = v + bn;
                }
            }
        }
    }
}

// ---------------------------------------------------------------------------
// Flash attention v7-32: swapped-operand flash on 32x32x16 MFMA -- one wave
// covers 32 q-rows per chunk (2x v6), halving per-row loads/instructions.
// Grid 1024 = 32 bh x 32 q-tiles(32 rows); 4-wave kv-split (c=wave; c+=4);
// bh = L&31 XCD affinity; longest tiles first (many small blocks backfill
// the imbalance -- R8 lesson).
//
//   QK^T swapped: st[T] = mfma32(K-tile, Q) -> D col = q = lane&31,
//   row = (reg&3)+8*(reg>>2)+4*hi. K rows loaded through the FIXED perm
//   swap-bits-2<->3 of (lane&31), which makes reg r of tile T hold key
//     kv0 + T*32 + 16*((r>>3)&1) + 8*hi + (r&3) + 4*((r>>2)&1)
//   so PV B-fragment pf[T*2+s'] = regs s'*8+0..7 IN ORDER (zero shuffles).
//   Softmax: 31 lane-local max + ONE shfl_xor(32). dm factorizes:
//   ew8[j], j=(r&3)+4*((r>>2)&1), w_k=j+8hi; sB[T*2+((r>>3)&1)]; per-lane
//   hq (32-row tile spans 2 h-values). PV: O^T[d][q], A=V^T rows d
//   (Dt*32 + lane&31), no permutation; d>=36 rows are zeroed padding.
// ---------------------------------------------------------------------------
__global__ __launch_bounds__(256, 2) void attn_kernel(
    const u16* __restrict__ qb, const u16* __restrict__ kb,
    const u16* __restrict__ vtb, u16* __restrict__ ob)
{
    __shared__ float sm[4][32], sl[4][32], so[4][32][37];  // 37: 5-stride banks
    int lane = threadIdx.x & 63, wave = threadIdx.x >> 6;
    int q5 = lane & 31, hi = lane >> 5, hi8 = hi * 8;
    int L = blockIdx.x;
    int bh = L & 31;                      // XCD affinity: xcd ~ L%8 = bh%8
    int qt = 31 - (L >> 5);               // longest kv ranges launch first
    int head = bh & 15, b = bh >> 4;
    int q0 = qt * 32;

    // Q as B-operand: lane holds Q[q0+q5][d16*16 + hi8 + e] (pre-scaled 1/6)
    const u16* qrow = qb + ((size_t)bh * SEQ_ + q0 + q5) * DKP_ + hi8;
    bf16x8 qf[4];
    #pragma unroll
    for (int d16 = 0; d16 < 4; d16++) qf[d16] = ldg8(qrow + d16 * 16);

    int tq = q0 >> 8;
    int hq = ((q0 >> 4) & 15) + (q5 >> 4);  // per-lane h-coord of q
    int qg = q0 + q5;                       // this lane's global q row
    int wq = q5 & 15;                       // w-coord of q
    float ew8[8];                           // w_k = j + 8*hi
    #pragma unroll
    for (int j = 0; j < 8; j++)
        ew8[j] = __expf((float)abs(wq - (j + hi8)) * (-1.0f / 33.0f));

    float m_i = -1e30f, l_i = 0.f;
    f32x16 oacc[2];
    #pragma unroll
    for (int Dt = 0; Dt < 2; Dt++)
        #pragma unroll
        for (int r = 0; r < 16; r++) oacc[Dt][r] = 0.f;

    // K-row permutation: swap bits 2<->3 of (lane&31)
    int kp = (q5 & ~12) | ((q5 & 4) << 1) | ((q5 & 8) >> 1);
    const u16* kbh = kb + (size_t)bh * SEQ_ * DKP_;
    const u16* vbh = vtb + (size_t)bh * DKP_ * SEQ_;

    int nch = (qt >> 1) + 1;              // chunks covering keys 0..q0+31
    for (int c = wave; c < nch; c += 4) {
        int kv0 = c * 64;
        bf16x8 kf[2][4], vf[2][4];
        #pragma unroll
        for (int T = 0; T < 2; T++) {
            const u16* kr = kbh + (size_t)(kv0 + T * 32 + kp) * DKP_ + hi8;
            #pragma unroll
            for (int d16 = 0; d16 < 4; d16++) kf[T][d16] = ldg8(kr + d16 * 16);
        }
        #pragma unroll
        for (int s = 0; s < 4; s++)       // V d-tile 0 (d = q5)
            vf[0][s] = ldg8(vbh + (size_t)q5 * SEQ_ + kv0 + s * 16 + hi8);
        // QK^T: st[T][r] = score(key(r,hi,T), q = q0+q5)
        f32x16 st[2];
        #pragma unroll
        for (int T = 0; T < 2; T++) {
            f32x16 tt;
            #pragma unroll
            for (int r = 0; r < 16; r++) tt[r] = 0.f;
            #pragma unroll
            for (int d16 = 0; d16 < 4; d16++)
                tt = MFMA32(kf[T][d16], qf[d16], tt);
            st[T] = tt;
        }
        #pragma unroll
        for (int s = 0; s < 4; s++)       // V d-tile 1 (d = 32+q5): hides
            vf[1][s] = ldg8(vbh + (size_t)(32 + q5) * SEQ_ + kv0 + s * 16 + hi8);
        // distance-decay: chunk spans 4 h values hk0..hk0+3 (never crosses t)
        int tk = kv0 >> 8, hk0 = (kv0 >> 4) & 15;
        float sB[4];
        #pragma unroll
        for (int i = 0; i < 4; i++)
            sB[i] = __expf((float)(abs(tq - tk) + abs(hq - hk0 - i))
                           * (-1.0f / 33.0f));
        float vv[2][16];
        #pragma unroll
        for (int T = 0; T < 2; T++)
            #pragma unroll
            for (int r = 0; r < 16; r++) {
                int j = (r & 3) + ((r >> 2) & 1) * 4;
                int hidx = T * 2 + ((r >> 3) & 1);
                vv[T][r] = st[T][r] * (sB[hidx] * ew8[j]);
            }
        if (c == nch - 1) {               // diagonal chunk: causal mask
            #pragma unroll
            for (int T = 0; T < 2; T++)
                #pragma unroll
                for (int r = 0; r < 16; r++) {
                    int key = kv0 + T * 32 + ((r >> 3) & 1) * 16 + hi8
                            + (r & 3) + ((r >> 2) & 1) * 4;
                    if (key > qg) vv[T][r] = -1e30f;
                }
        }
        // online softmax for q=q5: 31 local fmax + ONE shfl across hi halves
        float mloc = -1e30f;
        #pragma unroll
        for (int T = 0; T < 2; T++)
            #pragma unroll
            for (int r = 0; r < 16; r++) mloc = fmaxf(mloc, vv[T][r]);
        mloc = fmaxf(mloc, __shfl_xor(mloc, 32));
        float mn = fmaxf(m_i, mloc);
        float alpha = __expf(m_i - mn);
        m_i = mn;
        float p[2][16];
        float rs = 0.f;
        #pragma unroll
        for (int T = 0; T < 2; T++)
            #pragma unroll
            for (int r = 0; r < 16; r++) {
                p[T][r] = __expf(vv[T][r] - mn);
                rs += p[T][r];
            }
        rs += __shfl_xor(rs, 32);
        l_i = l_i * alpha + rs;
        #pragma unroll
        for (int Dt = 0; Dt < 2; Dt++)
            #pragma unroll
            for (int r = 0; r < 16; r++) oacc[Dt][r] *= alpha;
        // P^T B-fragments: pf[T*2+s'][e] = p[T][s'*8+e] (keys in order)
        bf16x8 pf[4];
        #pragma unroll
        for (int T = 0; T < 2; T++)
            #pragma unroll
            for (int sp = 0; sp < 2; sp++)
                #pragma unroll
                for (int e = 0; e < 8; e++)
                    pf[T * 2 + sp][e] = (__bf16)p[T][sp * 8 + e];
        // O^T[d][q] += V^T[d][k] * P^T[k][q]
        #pragma unroll
        for (int Dt = 0; Dt < 2; Dt++)
            #pragma unroll
            for (int s = 0; s < 4; s++)
                oacc[Dt] = MFMA32(vf[Dt][s], pf[s], oacc[Dt]);
    }

    // merge 4 waves' partials. Both hi halves carry identical m/l post-shfl.
    if (hi == 0) { sm[wave][q5] = m_i; sl[wave][q5] = l_i; }
    #pragma unroll
    for (int r = 0; r < 16; r++)          // Dt0: d = (r&3)+8*(r>>2)+4hi
        so[wave][q5][(r & 3) + 8 * (r >> 2) + 4 * hi] = oacc[0][r];
    if (hi == 0) {
        #pragma unroll
        for (int r = 0; r < 4; r++)       // Dt1: d = 32+r (only d<36 kept)
            so[wave][q5][32 + r] = oacc[1][r];
    }
    __syncthreads();
    for (int i = threadIdx.x; i < 32 * DK_; i += 256) {
        int row = i / DK_, col = i - row * DK_;
        float M = fmaxf(fmaxf(sm[0][row], sm[1][row]),
                        fmaxf(sm[2][row], sm[3][row]));
        float Lm = 0.f, O = 0.f;
        #pragma unroll
        for (int w = 0; w < 4; w++) {
            float f = __expf(sm[w][row] - M);
            Lm += f * sl[w][row];
            O += f * so[w][row][col];
        }
        ob[((size_t)b * SEQ_ + q0 + row) * E_ + head * DK_ + col] = f2bf(O / Lm);
    }
}

// ---------------------------------------------------------------------------
// Output: out = h + sum(p3[0..4)) (last layer's MLP2 partials fused here).
// ---------------------------------------------------------------------------
__global__ void out_kernel(const float* __restrict__ h,
                           const float* __restrict__ p3,
                           void* __restrict__ out,
                           const int* __restrict__ flagp)
{
    int isf32 = *flagp;
    size_t i = (size_t)blockIdx.x * blockDim.x + threadIdx.x;
    float v = h[i] + p3[i] + p3[i + PSTRIDE_] + p3[i + 2 * PSTRIDE_]
            + p3[i + 3 * PSTRIDE_];
    if (isf32) ((float*)out)[i] = v;
    else       ((u16*)out)[i] = f2bf(v);
}

// ---------------------------------------------------------------------------
extern "C" void kernel_launch(void* const* d_in, const int* in_sizes, int n_in,
                              void* d_out, int out_size, void* d_ws,
                              size_t ws_size, hipStream_t stream)
{
    const void* x    = d_in[0];
    const void* sos  = d_in[1];
    const void* pe0  = d_in[2];
    const void* pe1  = d_in[3];
    const void* pe2  = d_in[4];
    const void* ln1s = d_in[5];
    const void* ln1b = d_in[6];
    const void* wq   = d_in[7];
    const void* wk   = d_in[8];
    const void* wv   = d_in[9];
    const void* wo   = d_in[10];
    const void* bo   = d_in[11];
    const void* ln2s = d_in[12];
    const void* ln2b = d_in[13];
    const void* w1   = d_in[14];
    const void* b1   = d_in[15];
    const void* w2   = d_in[16];
    const void* b2   = d_in[17];

    char* ws = (char*)d_ws;
    u16*   qbuf  = (u16*)(ws + 0);          //  4 MB  [B,H,SEQ,64] bf16
    u16*   kbuf  = (u16*)(ws + 4194304);    //  4 MB
    u16*   vtbuf = (u16*)(ws + 8388608);    //  4 MB  [B,H,64,SEQ] bf16
    float* h     = (float*)(ws + 12582912); //  4.7 MB fp32 residual stream
    u16*   y     = (u16*)(ws + 17301504);   //  2.36 MB LN output
    u16*   o     = (u16*)(ws + 19660800);   //  2.36 MB attention output
    u16*   y1    = (u16*)(ws + 22020096);   //  9.4 MB MLP hidden
    u16*   wT    = (u16*)(ws + 31457280);   // 47.8 MB repacked weights (tiled)
    int*   flag  = (int*)(ws + 79233024);   // dtype flag
    float* p1    = (float*)(ws + 83886080); // 3 x 4.7 MB O-proj split-K partials
    float* p3    = (float*)(ws + 100663296);// 4 x 4.7 MB MLP2 split-K partials
    // (ws_size = 256 MiB per harness poison fill; top use here ~120 MB)

    // zero q/k/vt so DK->DKP padding lanes stay 0 (ws is 0xAA-poisoned)
    hipMemsetAsync(ws, 0, 12582912, stream);
    detect_kernel<<<1, 256, 0, stream>>>((const u16*)x, flag);
    repack_kernel<<<dim3(972, 1, 6), 256, 0, stream>>>(
        wq, wk, wv, wo, w1, w2, wT, flag);
    embed_kernel<<<ROWS_, E_, 0, stream>>>(x, sos, pe0, pe1, pe2, h, flag);

    for (int l = 0; l < NL_; l++) {
        u16* wTl = wT + (size_t)l * 3981312;
        if (l == 0)
            ln_kernel<0><<<512, 256, 0, stream>>>(h, y, nullptr, ln1s, ln1b,
                                                  l * E_, flag);
        else
            ln_kernel<4><<<512, 256, 0, stream>>>(h, y, p3, ln1s, ln1b,
                                                  l * E_, flag);
        gemm_kernel<0, 1><<<dim3(16, 9, 3), 512, 0, stream>>>(
            y, wTl, E_, nullptr, 0, nullptr, nullptr, qbuf, kbuf, vtbuf, flag);
        attn_kernel<<<dim3(1024), 256, 0, stream>>>(qbuf, kbuf, vtbuf, o);
        gemm_kernel<1, 3><<<dim3(16, 9, 3), 512, 0, stream>>>(
            o, wTl + 995328, E_, bo, l * E_, p1, nullptr, nullptr, nullptr, nullptr, flag);
        ln_kernel<3><<<512, 256, 0, stream>>>(h, y, p1, ln2s, ln2b,
                                              l * E_, flag);
        gemm_kernel<2, 1><<<dim3(16, 36, 1), 512, 0, stream>>>(
            y, wTl + 1327104, E_, b1, l * FF_, nullptr, y1, nullptr, nullptr, nullptr, flag);
        gemm_kernel<3, 4><<<dim3(16, 9, 4), 512, 0, stream>>>(
            y1, wTl + 2654208, FF_, b2, l * E_, p3, nullptr, nullptr, nullptr, nullptr, flag);
    }
    out_kernel<<<4608, 256, 0, stream>>>(h, p3, d_out, flag);
}